// Round 10
// baseline (19254.004 us; speedup 1.0000x reference)
//
#include <hip/hip_runtime.h>

typedef __attribute__((ext_vector_type(8))) short short8;
typedef __attribute__((ext_vector_type(4))) float f32x4;
typedef unsigned short ushort_t;
typedef unsigned long long u64_t;

#define T_STEPS 1024
#define NWG 260
#define NWG_MT 65

// Padded-segment geometry:
//   XN 512 (16 kb) | HI 308->320 (10 kb) | HC 204->224 (7 kb) | HM 512 (16 kb)
// One tile per WG; 4 waves split the tile's K-span (compile-time spans):
// L0 (16+10): w0 s1[0,7) w1 s1[7,14) w2 s1[14,16)+s2[0,5) w3 s2[5,10)   20 WGs r=0..19
// L1 (10+7):  w0 s1[0,5) w1 s1[5,10) w2 s2[0,4)           w3 s2[4,7)    13 WGs r=20..32
// L2 (7+16):  w0 s1[0,7) w1 s2[0,6)  w2 s2[6,11)          w3 s2[11,16)  32 WGs r=33..64
// Waves 1-3 write partials to dense LDS; wave 0 reduces + epilogue.
// Pipeline slot s: L0 step s, L1 step s-1, L2 step s-2; dataflow flags (r8/r9
// protocol, ranges renumbered; fan-in <= 78 -> 2 flags per poll lane).

#define PACK0 0
#define PACK1 1064960            // 20*26*2048
#define PACK2 1517568            // PACK1 + 13*17*2048

#define HI_P (64*320)
#define HC_P (64*224)
#define HM_P (64*512)

// ws offsets (bytes)
#define WS_BAR   0
#define WS_MU    4096
#define WS_RSTD  266240
#define WS_HI    528384
#define WS_HC    610304
#define WS_HM    667648
#define WS_PACK  798720

__device__ __forceinline__ ushort_t f2bf(float f) {
  union { float f; unsigned u; } un; un.f = f;
  unsigned r = (un.u + 0x7fffu + ((un.u >> 16) & 1u)) >> 16;
  return (ushort_t)r;
}

__device__ __forceinline__ void st2(ushort_t* p, ushort_t v) {
  __hip_atomic_store(p, v, __ATOMIC_RELAXED, __HIP_MEMORY_SCOPE_SYSTEM);
}
__device__ __forceinline__ u64_t ld8(const ushort_t* p) {
  return __hip_atomic_load((const u64_t*)p, __ATOMIC_RELAXED, __HIP_MEMORY_SCOPE_SYSTEM);
}
__device__ __forceinline__ unsigned ldf(const unsigned* p) {
  return __hip_atomic_load(p, __ATOMIC_RELAXED, __HIP_MEMORY_SCOPE_SYSTEM);
}
__device__ __forceinline__ void stf(unsigned* p, unsigned v) {
  __hip_atomic_store(p, v, __ATOMIC_RELAXED, __HIP_MEMORY_SCOPE_SYSTEM);
}

// ---------------- LayerNorm stats ----------------
__global__ __launch_bounds__(256) void ln_stats(const float* __restrict__ x,
                                                float* __restrict__ mu,
                                                float* __restrict__ rstd) {
  const int row = blockIdx.x * 4 + (threadIdx.x >> 6);
  const int lane = threadIdx.x & 63;
  const float* xr = x + (size_t)row * 512;
  float4 v0 = *(const float4*)(xr + lane * 8);
  float4 v1 = *(const float4*)(xr + lane * 8 + 4);
  float s = v0.x + v0.y + v0.z + v0.w + v1.x + v1.y + v1.z + v1.w;
  float q = v0.x*v0.x + v0.y*v0.y + v0.z*v0.z + v0.w*v0.w
          + v1.x*v1.x + v1.y*v1.y + v1.z*v1.z + v1.w*v1.w;
  for (int m = 1; m <= 32; m <<= 1) {
    s += __shfl_xor(s, m, 64);
    q += __shfl_xor(q, m, 64);
  }
  if (lane == 0) {
    float mean = s * (1.f / 512.f);
    float var = q * (1.f / 512.f) - mean * mean;
    mu[row] = mean;
    rstd[row] = rsqrtf(var + 1e-5f);
  }
}

// ---------------- init hidden state: bf16 linear padded, BOTH parities -------
__global__ void init_h(const float* __restrict__ h0,
                       ushort_t* hi, ushort_t* hc, ushort_t* hm) {
  int i = blockIdx.x * 256 + threadIdx.x;
  if (i >= 64 * 1056) return;
  int b = i / 1056, c = i % 1056;
  if (c < 320) {
    ushort_t v = (c < 308) ? f2bf(h0[b * 1024 + c]) : 0;
    st2(hi + b * 320 + c, v); st2(hi + HI_P + b * 320 + c, v);
  } else if (c < 544) {
    int col = c - 320;
    ushort_t v = (col < 204) ? f2bf(h0[b * 1024 + 308 + col]) : 0;
    st2(hc + b * 224 + col, v); st2(hc + HC_P + b * 224 + col, v);
  } else {
    int col = c - 544;
    ushort_t v = f2bf(h0[b * 1024 + 512 + col]);
    st2(hm + b * 512 + col, v); st2(hm + HM_P + b * 512 + col, v);
  }
}

// ---------------- pack masked weights ----------------
struct PackP {
  const float* w[12];
  const float* msk[3];
  ushort_t* pack;
};

__global__ __launch_bounds__(256) void ncp_pack(PackP P) {
  int u = blockIdx.x * 256 + threadIdx.x;
  int layer, rem, KB, K, H, s0p, s0l, s1l;
  size_t base;
  if (u < 133120)      { layer = 0; rem = u;          KB = 26; K = 820; H = 308; s0p = 512; s0l = 512; s1l = 308; base = PACK0; }
  else if (u < 189696) { layer = 1; rem = u - 133120; KB = 17; K = 512; H = 204; s0p = 320; s0l = 308; s1l = 204; base = PACK1; }
  else if (u < 378112) { layer = 2; rem = u - 189696; KB = 23; K = 716; H = 512; s0p = 224; s0l = 204; s1l = 512; base = PACK2; }
  else return;
  const int lane = rem & 63;
  const int mat = (rem >> 6) & 3;
  const int kb = (rem >> 8) % KB;
  const int nt = (rem >> 8) / KB;
  const float* W = P.w[layer * 4 + mat];
  const float* M = (mat < 2) ? P.msk[layer] : nullptr;
  const int n = nt * 16 + (lane & 15);
  const int kbase = kb * 32 + ((lane >> 4) << 3);
  ushort_t* dst = P.pack + base + (size_t)rem * 8;
#pragma unroll
  for (int j = 0; j < 8; ++j) {
    const int kp = kbase + j;
    int ko;
    if (kp < s0p) ko = (kp < s0l) ? kp : -1;
    else { const int ks = kp - s0p; ko = (ks < s1l) ? (s0l + ks) : -1; }
    float v = 0.f;
    if (n < H && ko >= 0) {
      v = W[(size_t)n * K + ko];
      if (M) v *= M[(size_t)n * K + ko];
    }
    dst[j] = f2bf(v);
  }
}

// ---------------- main persistent kernel ----------------
struct MainP {
  const float* x;
  const float* gamma;
  const float* beta;
  const float* bias[12];
  const float* mu;
  const float* rstd;
  ushort_t* hi;
  ushort_t* hc;
  ushort_t* hm;
  const ushort_t* pack;
  unsigned* bar;
  float* y;
  float* hfin;
};

// depth-4 software-pipelined MFMA span over one LDS region
template<int KBT>
__device__ __forceinline__ void mfma_span(const ushort_t* __restrict__ bp,
                                          const ushort_t* __restrict__ lds, int lane,
                                          f32x4& a0, f32x4& a1, f32x4& a2, f32x4& a3) {
  const ushort_t* bb = bp + lane * 8;
  short8 buf[4][4];
#pragma unroll
  for (int kb = 0; kb < 4 && kb < KBT; ++kb) {
    const ushort_t* q = bb + (size_t)kb * 2048;
    buf[kb][0] = *(const short8*)(q);
    buf[kb][1] = *(const short8*)(q + 512);
    buf[kb][2] = *(const short8*)(q + 1024);
    buf[kb][3] = *(const short8*)(q + 1536);
  }
#pragma unroll
  for (int kb = 0; kb < KBT; ++kb) {
    short8 av = *(const short8*)(lds + (size_t)(kb * 64 + lane) * 8);
    a0 = __builtin_amdgcn_mfma_f32_16x16x32_bf16(av, buf[kb & 3][0], a0, 0, 0, 0);
    a1 = __builtin_amdgcn_mfma_f32_16x16x32_bf16(av, buf[kb & 3][1], a1, 0, 0, 0);
    a2 = __builtin_amdgcn_mfma_f32_16x16x32_bf16(av, buf[kb & 3][2], a2, 0, 0, 0);
    a3 = __builtin_amdgcn_mfma_f32_16x16x32_bf16(av, buf[kb & 3][3], a3, 0, 0, 0);
    if (kb + 4 < KBT) {
      const ushort_t* q = bb + (size_t)(kb + 4) * 2048;
      buf[kb & 3][0] = *(const short8*)(q);
      buf[kb & 3][1] = *(const short8*)(q + 512);
      buf[kb & 3][2] = *(const short8*)(q + 1024);
      buf[kb & 3][3] = *(const short8*)(q + 1536);
    }
  }
}

// epilogue by wave 0 after 4-way accumulation
template<int H, int STP>
__device__ __forceinline__ void epilogue(const f32x4* A, int nt, int lane, int mtile,
                                         int t, bool last,
                                         const float* __restrict__ bp1, const float* __restrict__ bp2,
                                         const float* __restrict__ bpa, const float* __restrict__ bpb,
                                         ushort_t* __restrict__ hout, float* __restrict__ y,
                                         float* __restrict__ hfin, int hoff) {
  const int n = nt * 16 + (lane & 15);
  if (n < H) {
    float c1 = bp1[n], c2 = bp2[n], ca = bpa[n], cb = bpb[n];
    const int r0 = (lane >> 4) << 2;
#pragma unroll
    for (int j = 0; j < 4; ++j) {
      int brow = mtile * 16 + r0 + j;
      float s = 1.f / (1.f + __expf(-(A[2][j] + ca + A[3][j] + cb)));
      float f1 = 1.f - 2.f / (1.f + __expf(2.f * (A[0][j] + c1)));
      float f2 = 1.f - 2.f / (1.f + __expf(2.f * (A[1][j] + c2)));
      float v = f1 * (1.f - s) + s * f2;
      st2(hout + (size_t)brow * STP + n, f2bf(v));
      if (y) y[((size_t)brow * T_STEPS + t) * 512 + n] = v;
      if (last) hfin[brow * 1024 + hoff + n] = v;
    }
  }
}

// stage up to two bf16 padded segments; coalesced 8B units, all loads issued
// before any LDS write -> ~1 coherent-point round trip.
template<int S1, int ST1, int S2, int ST2>
__device__ __forceinline__ void stage2(ushort_t* __restrict__ r1, const ushort_t* __restrict__ h1,
                                       ushort_t* __restrict__ r2, const ushort_t* __restrict__ h2,
                                       int tid) {
  constexpr int U1 = S1 * 2, U2 = S2 * 2;
  constexpr int I1 = (U1 + 255) / 256;
  constexpr int I2 = (U2 + 255) / 256;
  u64_t a[I1];
  u64_t b[I2 > 0 ? I2 : 1];
#pragma unroll
  for (int i = 0; i < I1; ++i) {
    const int u = tid + i * 256;
    if ((U1 & 255) == 0 || u < U1) {
      const int slot = u >> 1;
      a[i] = ld8(h1 + (slot & 15) * ST1 + (slot >> 6) * 32 + ((slot >> 4) & 3) * 8 + (u & 1) * 4);
    }
  }
  if constexpr (S2 > 0) {
#pragma unroll
    for (int i = 0; i < I2; ++i) {
      const int u = tid + i * 256;
      if ((U2 & 255) == 0 || u < U2) {
        const int slot = u >> 1;
        b[i] = ld8(h2 + (slot & 15) * ST2 + (slot >> 6) * 32 + ((slot >> 4) & 3) * 8 + (u & 1) * 4);
      }
    }
  }
#pragma unroll
  for (int i = 0; i < I1; ++i) {
    const int u = tid + i * 256;
    if ((U1 & 255) == 0 || u < U1) *(u64_t*)(r1 + (size_t)u * 4) = a[i];
  }
  if constexpr (S2 > 0) {
#pragma unroll
    for (int i = 0; i < I2; ++i) {
      const int u = tid + i * 256;
      if ((U2 & 255) == 0 || u < U2) *(u64_t*)(r2 + (size_t)u * 4) = b[i];
    }
  }
}

__device__ __forceinline__ void stage_xn(ushort_t* __restrict__ XN, const MainP& P,
                                         int mtile, int tid, int t) {
#pragma unroll
  for (int i = 0; i < 4; ++i) {
    const int s = tid + i * 256;
    const int ln = s & 63;
    const int brow = mtile * 16 + (ln & 15);
    const int kbase = (s >> 6) * 32 + ((ln >> 4) << 3);
    const float muv = P.mu[brow * T_STEPS + t];
    const float rsv = P.rstd[brow * T_STEPS + t];
    const float* xrow = P.x + ((size_t)brow * T_STEPS + t) * 512;
    short8 w;
#pragma unroll
    for (int j = 0; j < 8; ++j)
      w[j] = f2bf((xrow[kbase + j] - muv) * rsv * P.gamma[kbase + j] + P.beta[kbase + j]);
    *(short8*)(XN + (size_t)s * 8) = w;
  }
}

__global__ __launch_bounds__(256) void ncp_main(MainP P) {
  const int tid = threadIdx.x;
  const int lane = tid & 63;
  const int wv = tid >> 6;        // role 0..3: K-span of the WG's single tile
  const int wg = blockIdx.x;
  const int mt = wg / NWG_MT;     // 0..3
  const int r  = wg % NWG_MT;     // 0..19: L0, 20..32: L1, 33..64: L2

  __shared__ __align__(16) ushort_t Alds[2688 * 8];  // 42 KB staging (L0 layout)
  __shared__ __align__(16) f32x4 pacc[768];          // 12 KB partials (dense)
  // L0: XN parity0 [0..1023], XN parity1 [1024..2047], HI [2048..2687]
  // L1: HI [0..639], HC [640..1087]
  // L2: HC [0..447], HM [448..1471]

  // ---- dataflow-flag setup (65 WGs/mtile; fan-in <= 78 -> 2 flags/lane) ----
  unsigned* wf = P.bar + mt * 256;       // wflag[0..64]
  unsigned* rf = wf + 128;               // rflag[0..64]
  int wa, wb, ra, rb;
  if (r < 20)      { wa = 0;  wb = 20; ra = 0;  rb = 33; }
  else if (r < 33) { wa = 0;  wb = 33; ra = 20; rb = 65; }
  else             { wa = 20; wb = 65; ra = 33; rb = 65; }
  const int nw = wb - wa, ntot = nw + (rb - ra);
  const unsigned *p1 = wf, *p2 = wf;
  bool a1 = false, a2 = false;
  {
    const int k1 = lane, k2 = lane + 64;
    if (k1 < ntot) { p1 = (k1 < nw) ? wf + wa + k1 : rf + ra + (k1 - nw); a1 = true; }
    if (k2 < ntot) { p2 = (k2 < nw) ? wf + wa + k2 : rf + ra + (k2 - nw); a2 = true; }
  }

  if (r < 20) stage_xn(Alds, P, mt, tid, 0);  // prologue XN(0) into parity-0

  for (int s = 0; s < T_STEPS + 2; ++s) {
    // ---- wait ----
    if (wv == 0) {
      const unsigned need = (unsigned)s;
      for (;;) {
        unsigned v1 = a1 ? ldf(p1) : 0xFFFFFFFFu;
        unsigned v2 = a2 ? ldf(p2) : 0xFFFFFFFFu;
        unsigned v = v1 < v2 ? v1 : v2;
        if (__all((int)(v >= need))) break;
      }
    }
    __syncthreads();

    // ---- per-layer slot state ----
    int nt = 0, tstep = 0;
    bool on = false;
    if (r < 20)      { nt = r;      tstep = s;     on = (s < T_STEPS); }
    else if (r < 33) { nt = r - 20; tstep = s - 1; on = (s >= 1 && s <= T_STEPS); }
    else             { nt = r - 33; tstep = s - 2; on = (s >= 2); }
    const bool last = (tstep == T_STEPS - 1);

    // ---- stage ----
    if (r < 20) {
      if (s < T_STEPS)
        stage2<640, 320, 0, 0>(Alds + 2048 * 8,
                               P.hi + (((s - 1) & 1) * 64 + mt * 16) * 320,
                               nullptr, nullptr, tid);
    } else if (r < 33) {
      if (s >= 1 && s <= T_STEPS)
        stage2<640, 320, 448, 224>(Alds, P.hi + (((s - 1) & 1) * 64 + mt * 16) * 320,
                                   Alds + 640 * 8,
                                   P.hc + (((s - 2) & 1) * 64 + mt * 16) * 224, tid);
    } else {
      if (s >= 2)
        stage2<448, 224, 1024, 512>(Alds, P.hc + (((s - 2) & 1) * 64 + mt * 16) * 224,
                                    Alds + 448 * 8,
                                    P.hm + (((s - 3) & 1) * 64 + mt * 16) * 512, tid);
    }
    __syncthreads();                      // (A) LDS staged
    if (tid == 0) stf(rf + r, (unsigned)(s + 1));

    // ---- K-spans (4-way split, compile-time) ----
    f32x4 A[4];
#pragma unroll
    for (int j = 0; j < 4; ++j) A[j] = {0.f, 0.f, 0.f, 0.f};
    if (on) {
      if (r < 20) {
        const ushort_t* bp = P.pack + PACK0 + (size_t)nt * 26 * 2048;
        const ushort_t* xn = Alds + (s & 1) * (1024 * 8);
        const ushort_t* hi = Alds + 2048 * 8;
        if (wv == 0)      mfma_span<7>(bp,             xn,          lane, A[0], A[1], A[2], A[3]);
        else if (wv == 1) mfma_span<7>(bp + 7 * 2048,  xn + 7*512,  lane, A[0], A[1], A[2], A[3]);
        else if (wv == 2) { mfma_span<2>(bp + 14 * 2048, xn + 14*512, lane, A[0], A[1], A[2], A[3]);
                            mfma_span<5>(bp + 16 * 2048, hi,          lane, A[0], A[1], A[2], A[3]); }
        else              mfma_span<5>(bp + 21 * 2048, hi + 5*512,  lane, A[0], A[1], A[2], A[3]);
      } else if (r < 33) {
        const ushort_t* bp = P.pack + PACK1 + (size_t)nt * 17 * 2048;
        const ushort_t* l1 = Alds;
        const ushort_t* l2 = Alds + 640 * 8;
        if (wv == 0)      mfma_span<5>(bp,             l1,          lane, A[0], A[1], A[2], A[3]);
        else if (wv == 1) mfma_span<5>(bp + 5 * 2048,  l1 + 5*512,  lane, A[0], A[1], A[2], A[3]);
        else if (wv == 2) mfma_span<4>(bp + 10 * 2048, l2,          lane, A[0], A[1], A[2], A[3]);
        else              mfma_span<3>(bp + 14 * 2048, l2 + 4*512,  lane, A[0], A[1], A[2], A[3]);
      } else {
        const ushort_t* bp = P.pack + PACK2 + (size_t)nt * 23 * 2048;
        const ushort_t* l1 = Alds;
        const ushort_t* l2 = Alds + 448 * 8;
        if (wv == 0)      mfma_span<7>(bp,             l1,          lane, A[0], A[1], A[2], A[3]);
        else if (wv == 1) mfma_span<6>(bp + 7 * 2048,  l2,          lane, A[0], A[1], A[2], A[3]);
        else if (wv == 2) mfma_span<5>(bp + 13 * 2048, l2 + 6*512,  lane, A[0], A[1], A[2], A[3]);
        else              mfma_span<5>(bp + 18 * 2048, l2 + 11*512, lane, A[0], A[1], A[2], A[3]);
      }
      if (wv != 0) {
#pragma unroll
        for (int j = 0; j < 4; ++j) pacc[(wv - 1) * 256 + j * 64 + lane] = A[j];
      }
    }
    __syncthreads();                      // (A2) partials ready

    // ---- reduce + epilogue (wave 0) ----
    if (on && wv == 0) {
#pragma unroll
      for (int j = 0; j < 4; ++j)
        A[j] = A[j] + pacc[j * 64 + lane] + pacc[256 + j * 64 + lane] + pacc[512 + j * 64 + lane];
      if (r < 20)
        epilogue<308, 320>(A, nt, lane, mt, tstep, last,
                           P.bias[0], P.bias[1], P.bias[2], P.bias[3],
                           P.hi + (tstep & 1) * HI_P, nullptr, P.hfin, 0);
      else if (r < 33)
        epilogue<204, 224>(A, nt, lane, mt, tstep, last,
                           P.bias[4], P.bias[5], P.bias[6], P.bias[7],
                           P.hc + (tstep & 1) * HC_P, nullptr, P.hfin, 308);
      else
        epilogue<512, 512>(A, nt, lane, mt, tstep, last,
                           P.bias[8], P.bias[9], P.bias[10], P.bias[11],
                           P.hm + (tstep & 1) * HM_P, P.y, P.hfin, 512);
    }
    asm volatile("s_waitcnt vmcnt(0)" ::: "memory");
    __syncthreads();                      // (B) all h stores at coherent point
    if (tid == 0) stf(wf + r, (unsigned)(s + 1));

    // ---- off critical path: L0 prefetches XN(s+1) into other parity ----
    if (r < 20 && s + 1 < T_STEPS)
      stage_xn(Alds + ((s + 1) & 1) * (1024 * 8), P, mt, tid, s + 1);
  }
}

extern "C" void kernel_launch(void* const* d_in, const int* in_sizes, int n_in,
                              void* d_out, int out_size, void* d_ws, size_t ws_size,
                              hipStream_t stream) {
  const float* x     = (const float*)d_in[27];
  const float* h0    = (const float*)d_in[28];
  const float* gamma = (const float*)d_in[29];
  const float* beta  = (const float*)d_in[30];

  char* ws = (char*)d_ws;
  unsigned* bar = (unsigned*)(ws + WS_BAR);
  float* mu   = (float*)(ws + WS_MU);
  float* rstd = (float*)(ws + WS_RSTD);
  ushort_t* hi = (ushort_t*)(ws + WS_HI);
  ushort_t* hc = (ushort_t*)(ws + WS_HC);
  ushort_t* hm = (ushort_t*)(ws + WS_HM);
  ushort_t* pack = (ushort_t*)(ws + WS_PACK);

  float* y = (float*)d_out;
  float* hfin = y + (size_t)64 * 1024 * 512;

  hipMemsetAsync(bar, 0, 4096, stream);

  ln_stats<<<dim3(16384), dim3(256), 0, stream>>>(x, mu, rstd);
  init_h<<<dim3(264), dim3(256), 0, stream>>>(h0, hi, hc, hm);

  PackP pp;
  for (int l = 0; l < 3; ++l) {
    for (int m = 0; m < 4; ++m) pp.w[l * 4 + m] = (const float*)d_in[l * 9 + 2 * m];
    pp.msk[l] = (const float*)d_in[l * 9 + 8];
  }
  pp.pack = pack;
  ncp_pack<<<dim3(1477), dim3(256), 0, stream>>>(pp);

  MainP mp;
  mp.x = x; mp.gamma = gamma; mp.beta = beta;
  for (int l = 0; l < 3; ++l)
    for (int m = 0; m < 4; ++m) mp.bias[l * 4 + m] = (const float*)d_in[l * 9 + 2 * m + 1];
  mp.mu = mu; mp.rstd = rstd;
  mp.hi = hi; mp.hc = hc; mp.hm = hm;
  mp.pack = pack; mp.bar = bar;
  mp.y = y; mp.hfin = hfin;
  ncp_main<<<dim3(NWG), dim3(256), 0, stream>>>(mp);
}

// Round 12
// 9260.220 us; speedup vs baseline: 2.0792x; 2.0792x over previous
//
#include <hip/hip_runtime.h>

typedef __attribute__((ext_vector_type(8))) short short8;
typedef __attribute__((ext_vector_type(4))) float f32x4;
typedef unsigned short ushort_t;
typedef unsigned long long u64_t;

#define T_STEPS 1024
#define NWG 132
#define NWG_MT 33

// r9 geometry (best measured): 33 WGs/mtile, 2 tiles/WG, wave-pair K-split.
//   XN 512 (16 kb) | HI 308->320 (10 kb) | HC 204->224 (7 kb) | HM 512 (16 kb)
// L0: A = XN ++ HI  KB=26 (16+10)  NT=20  (10 WGs/mtile, r=0..9)
// L1: A = HI ++ HC  KB=17 (10+7)   NT=13  (7 WGs/mtile,  r=10..16)
// L2: A = HC ++ HM  KB=23 (7+16)   NT=32  (16 WGs/mtile, r=17..32)
// Pipeline slot s: L0 step s, L1 step s-1, L2 step s-2; dataflow flags.
// r12 = r11 with the nontemporal-load type fixed (native f32x4, not float4):
// dense pacc (no LDS conflicts), nontemporal x/y streams (protect L2-resident
// packed weights), y/hfin stores deferred past wf post.

#define PACK0 0
#define PACK1 1064960            // 20*26*2048
#define PACK2 1517568            // PACK1 + 13*17*2048

#define HI_P (64*320)
#define HC_P (64*224)
#define HM_P (64*512)

// ws offsets (bytes)
#define WS_BAR   0
#define WS_MU    4096
#define WS_RSTD  266240
#define WS_HI    528384
#define WS_HC    610304
#define WS_HM    667648
#define WS_PACK  798720

__device__ __forceinline__ ushort_t f2bf(float f) {
  union { float f; unsigned u; } un; un.f = f;
  unsigned r = (un.u + 0x7fffu + ((un.u >> 16) & 1u)) >> 16;
  return (ushort_t)r;
}

__device__ __forceinline__ void st2(ushort_t* p, ushort_t v) {
  __hip_atomic_store(p, v, __ATOMIC_RELAXED, __HIP_MEMORY_SCOPE_SYSTEM);
}
__device__ __forceinline__ u64_t ld8(const ushort_t* p) {
  return __hip_atomic_load((const u64_t*)p, __ATOMIC_RELAXED, __HIP_MEMORY_SCOPE_SYSTEM);
}
__device__ __forceinline__ unsigned ldf(const unsigned* p) {
  return __hip_atomic_load(p, __ATOMIC_RELAXED, __HIP_MEMORY_SCOPE_SYSTEM);
}
__device__ __forceinline__ void stf(unsigned* p, unsigned v) {
  __hip_atomic_store(p, v, __ATOMIC_RELAXED, __HIP_MEMORY_SCOPE_SYSTEM);
}

// ---------------- LayerNorm stats ----------------
__global__ __launch_bounds__(256) void ln_stats(const float* __restrict__ x,
                                                float* __restrict__ mu,
                                                float* __restrict__ rstd) {
  const int row = blockIdx.x * 4 + (threadIdx.x >> 6);
  const int lane = threadIdx.x & 63;
  const float* xr = x + (size_t)row * 512;
  float4 v0 = *(const float4*)(xr + lane * 8);
  float4 v1 = *(const float4*)(xr + lane * 8 + 4);
  float s = v0.x + v0.y + v0.z + v0.w + v1.x + v1.y + v1.z + v1.w;
  float q = v0.x*v0.x + v0.y*v0.y + v0.z*v0.z + v0.w*v0.w
          + v1.x*v1.x + v1.y*v1.y + v1.z*v1.z + v1.w*v1.w;
  for (int m = 1; m <= 32; m <<= 1) {
    s += __shfl_xor(s, m, 64);
    q += __shfl_xor(q, m, 64);
  }
  if (lane == 0) {
    float mean = s * (1.f / 512.f);
    float var = q * (1.f / 512.f) - mean * mean;
    mu[row] = mean;
    rstd[row] = rsqrtf(var + 1e-5f);
  }
}

// ---------------- init hidden state: bf16 linear padded, BOTH parities -------
__global__ void init_h(const float* __restrict__ h0,
                       ushort_t* hi, ushort_t* hc, ushort_t* hm) {
  int i = blockIdx.x * 256 + threadIdx.x;
  if (i >= 64 * 1056) return;
  int b = i / 1056, c = i % 1056;
  if (c < 320) {
    ushort_t v = (c < 308) ? f2bf(h0[b * 1024 + c]) : 0;
    st2(hi + b * 320 + c, v); st2(hi + HI_P + b * 320 + c, v);
  } else if (c < 544) {
    int col = c - 320;
    ushort_t v = (col < 204) ? f2bf(h0[b * 1024 + 308 + col]) : 0;
    st2(hc + b * 224 + col, v); st2(hc + HC_P + b * 224 + col, v);
  } else {
    int col = c - 544;
    ushort_t v = f2bf(h0[b * 1024 + 512 + col]);
    st2(hm + b * 512 + col, v); st2(hm + HM_P + b * 512 + col, v);
  }
}

// ---------------- pack masked weights ----------------
struct PackP {
  const float* w[12];
  const float* msk[3];
  ushort_t* pack;
};

__global__ __launch_bounds__(256) void ncp_pack(PackP P) {
  int u = blockIdx.x * 256 + threadIdx.x;
  int layer, rem, KB, K, H, s0p, s0l, s1l;
  size_t base;
  if (u < 133120)      { layer = 0; rem = u;          KB = 26; K = 820; H = 308; s0p = 512; s0l = 512; s1l = 308; base = PACK0; }
  else if (u < 189696) { layer = 1; rem = u - 133120; KB = 17; K = 512; H = 204; s0p = 320; s0l = 308; s1l = 204; base = PACK1; }
  else if (u < 378112) { layer = 2; rem = u - 189696; KB = 23; K = 716; H = 512; s0p = 224; s0l = 204; s1l = 512; base = PACK2; }
  else return;
  const int lane = rem & 63;
  const int mat = (rem >> 6) & 3;
  const int kb = (rem >> 8) % KB;
  const int nt = (rem >> 8) / KB;
  const float* W = P.w[layer * 4 + mat];
  const float* M = (mat < 2) ? P.msk[layer] : nullptr;
  const int n = nt * 16 + (lane & 15);
  const int kbase = kb * 32 + ((lane >> 4) << 3);
  ushort_t* dst = P.pack + base + (size_t)rem * 8;
#pragma unroll
  for (int j = 0; j < 8; ++j) {
    const int kp = kbase + j;
    int ko;
    if (kp < s0p) ko = (kp < s0l) ? kp : -1;
    else { const int ks = kp - s0p; ko = (ks < s1l) ? (s0l + ks) : -1; }
    float v = 0.f;
    if (n < H && ko >= 0) {
      v = W[(size_t)n * K + ko];
      if (M) v *= M[(size_t)n * K + ko];
    }
    dst[j] = f2bf(v);
  }
}

// ---------------- main persistent kernel ----------------
struct MainP {
  const float* x;
  const float* gamma;
  const float* beta;
  const float* bias[12];
  const float* mu;
  const float* rstd;
  ushort_t* hi;
  ushort_t* hc;
  ushort_t* hm;
  const ushort_t* pack;
  unsigned* bar;
  float* y;
  float* hfin;
};

// depth-4 software-pipelined MFMA span over one LDS region
template<int KBT>
__device__ __forceinline__ void mfma_span(const ushort_t* __restrict__ bp,
                                          const ushort_t* __restrict__ lds, int lane,
                                          f32x4& a0, f32x4& a1, f32x4& a2, f32x4& a3) {
  const ushort_t* bb = bp + lane * 8;
  short8 buf[4][4];
#pragma unroll
  for (int kb = 0; kb < 4 && kb < KBT; ++kb) {
    const ushort_t* q = bb + (size_t)kb * 2048;
    buf[kb][0] = *(const short8*)(q);
    buf[kb][1] = *(const short8*)(q + 512);
    buf[kb][2] = *(const short8*)(q + 1024);
    buf[kb][3] = *(const short8*)(q + 1536);
  }
#pragma unroll
  for (int kb = 0; kb < KBT; ++kb) {
    short8 av = *(const short8*)(lds + (size_t)(kb * 64 + lane) * 8);
    a0 = __builtin_amdgcn_mfma_f32_16x16x32_bf16(av, buf[kb & 3][0], a0, 0, 0, 0);
    a1 = __builtin_amdgcn_mfma_f32_16x16x32_bf16(av, buf[kb & 3][1], a1, 0, 0, 0);
    a2 = __builtin_amdgcn_mfma_f32_16x16x32_bf16(av, buf[kb & 3][2], a2, 0, 0, 0);
    a3 = __builtin_amdgcn_mfma_f32_16x16x32_bf16(av, buf[kb & 3][3], a3, 0, 0, 0);
    if (kb + 4 < KBT) {
      const ushort_t* q = bb + (size_t)(kb + 4) * 2048;
      buf[kb & 3][0] = *(const short8*)(q);
      buf[kb & 3][1] = *(const short8*)(q + 512);
      buf[kb & 3][2] = *(const short8*)(q + 1024);
      buf[kb & 3][3] = *(const short8*)(q + 1536);
    }
  }
}

// h-only epilogue: apply gates, store h (st2), keep v in regs for deferred y.
template<int H, int STP>
__device__ __forceinline__ void epi_h(const f32x4* A, int nt, int lane, int mtile,
                                      const float* __restrict__ bp1, const float* __restrict__ bp2,
                                      const float* __restrict__ bpa, const float* __restrict__ bpb,
                                      ushort_t* __restrict__ hout, float* vk) {
  const int n = nt * 16 + (lane & 15);
  const int r0 = (lane >> 4) << 2;
#pragma unroll
  for (int j = 0; j < 4; ++j) vk[j] = 0.f;
  if (n < H) {
    float c1 = bp1[n], c2 = bp2[n], ca = bpa[n], cb = bpb[n];
#pragma unroll
    for (int j = 0; j < 4; ++j) {
      int brow = mtile * 16 + r0 + j;
      float sg = 1.f / (1.f + __expf(-(A[2][j] + ca + A[3][j] + cb)));
      float f1 = 1.f - 2.f / (1.f + __expf(2.f * (A[0][j] + c1)));
      float f2 = 1.f - 2.f / (1.f + __expf(2.f * (A[1][j] + c2)));
      float v = f1 * (1.f - sg) + sg * f2;
      vk[j] = v;
      st2(hout + (size_t)brow * STP + n, f2bf(v));
    }
  }
}

// stage up to two bf16 padded segments; coalesced 8B units, all loads issued
// before any LDS write -> ~1 coherent-point round trip.
template<int S1, int ST1, int S2, int ST2>
__device__ __forceinline__ void stage2(ushort_t* __restrict__ r1, const ushort_t* __restrict__ h1,
                                       ushort_t* __restrict__ r2, const ushort_t* __restrict__ h2,
                                       int tid) {
  constexpr int U1 = S1 * 2, U2 = S2 * 2;
  constexpr int I1 = (U1 + 255) / 256;
  constexpr int I2 = (U2 + 255) / 256;
  u64_t a[I1];
  u64_t b[I2 > 0 ? I2 : 1];
#pragma unroll
  for (int i = 0; i < I1; ++i) {
    const int u = tid + i * 256;
    if ((U1 & 255) == 0 || u < U1) {
      const int slot = u >> 1;
      a[i] = ld8(h1 + (slot & 15) * ST1 + (slot >> 6) * 32 + ((slot >> 4) & 3) * 8 + (u & 1) * 4);
    }
  }
  if constexpr (S2 > 0) {
#pragma unroll
    for (int i = 0; i < I2; ++i) {
      const int u = tid + i * 256;
      if ((U2 & 255) == 0 || u < U2) {
        const int slot = u >> 1;
        b[i] = ld8(h2 + (slot & 15) * ST2 + (slot >> 6) * 32 + ((slot >> 4) & 3) * 8 + (u & 1) * 4);
      }
    }
  }
#pragma unroll
  for (int i = 0; i < I1; ++i) {
    const int u = tid + i * 256;
    if ((U1 & 255) == 0 || u < U1) *(u64_t*)(r1 + (size_t)u * 4) = a[i];
  }
  if constexpr (S2 > 0) {
#pragma unroll
    for (int i = 0; i < I2; ++i) {
      const int u = tid + i * 256;
      if ((U2 & 255) == 0 || u < U2) *(u64_t*)(r2 + (size_t)u * 4) = b[i];
    }
  }
}

__device__ __forceinline__ void stage_xn(ushort_t* __restrict__ XN, const MainP& P,
                                         int mtile, int tid, int t) {
#pragma unroll
  for (int i = 0; i < 4; ++i) {
    const int s = tid + i * 256;
    const int ln = s & 63;
    const int brow = mtile * 16 + (ln & 15);
    const int kbase = (s >> 6) * 32 + ((ln >> 4) << 3);
    const float muv = P.mu[brow * T_STEPS + t];
    const float rsv = P.rstd[brow * T_STEPS + t];
    // nontemporal x loads (native vector type): x streams once; keep out of L2
    const f32x4* xr = (const f32x4*)(P.x + ((size_t)brow * T_STEPS + t) * 512 + kbase);
    f32x4 xv0 = __builtin_nontemporal_load(xr);
    f32x4 xv1 = __builtin_nontemporal_load(xr + 1);
    const f32x4 g0 = *(const f32x4*)(P.gamma + kbase);
    const f32x4 g1 = *(const f32x4*)(P.gamma + kbase + 4);
    const f32x4 b0 = *(const f32x4*)(P.beta + kbase);
    const f32x4 b1 = *(const f32x4*)(P.beta + kbase + 4);
    short8 w;
#pragma unroll
    for (int j = 0; j < 4; ++j) w[j] = f2bf((xv0[j] - muv) * rsv * g0[j] + b0[j]);
#pragma unroll
    for (int j = 0; j < 4; ++j) w[4 + j] = f2bf((xv1[j] - muv) * rsv * g1[j] + b1[j]);
    *(short8*)(XN + (size_t)s * 8) = w;
  }
}

__global__ __launch_bounds__(256) void ncp_main(MainP P) {
  const int tid = threadIdx.x;
  const int lane = tid & 63;
  const int wv = tid >> 6;
  const int role = wv & 1;        // 0 = seg1 span + epilogue, 1 = seg2 span
  const int tslot = wv >> 1;      // which of the WG's 2 tiles
  const int wg = blockIdx.x;
  const int mt = wg / NWG_MT;     // 0..3
  const int r  = wg % NWG_MT;     // 0..9: L0, 10..16: L1, 17..32: L2

  __shared__ __align__(16) ushort_t Alds[2688 * 8];  // 42 KB staging (L0 layout)
  __shared__ __align__(16) f32x4 pacc[2][256];       // 8 KB partials (dense, conflict-free)
  // L0: XN parity0 [0..1023], XN parity1 [1024..2047], HI [2048..2687]
  // L1: HI [0..639], HC [640..1087]
  // L2: HC [0..447], HM [448..1471]

  // ---- dataflow-flag setup (r9 protocol) ----
  unsigned* wf = P.bar + mt * 128;       // wflag[0..32]
  unsigned* rf = wf + 64;                // rflag[0..32]
  int wa, wb, ra, rb;
  if (r < 10)      { wa = 0;  wb = 10; ra = 0;  rb = 17; }
  else if (r < 17) { wa = 0;  wb = 17; ra = 10; rb = 33; }
  else             { wa = 10; wb = 33; ra = 17; rb = 33; }
  const int nw = wb - wa, nr = rb - ra;
  const unsigned* paddr = wf;
  bool pact = false;
  if (lane < nw)           { paddr = wf + wa + lane;        pact = true; }
  else if (lane < nw + nr) { paddr = rf + ra + (lane - nw); pact = true; }

  if (r < 10) stage_xn(Alds, P, mt, tid, 0);  // prologue XN(0) into parity-0

  for (int s = 0; s < T_STEPS + 2; ++s) {
    // ---- wait ----
    if (wv == 0) {
      const unsigned need = (unsigned)s;
      for (;;) {
        unsigned v = pact ? ldf(paddr) : 0xFFFFFFFFu;
        if (__all((int)(v >= need))) break;
      }
    }
    __syncthreads();

    // ---- per-layer slot state ----
    int nt = 0, tstep = 0;
    bool on = false;
    if (r < 10)      { nt = r * 2 + tslot;        tstep = s;     on = (s < T_STEPS); }
    else if (r < 17) { nt = (r - 10) * 2 + tslot; tstep = s - 1; on = (s >= 1 && s <= T_STEPS) && (nt < 13); }
    else             { nt = (r - 17) * 2 + tslot; tstep = s - 2; on = (s >= 2); }
    const bool last = (tstep == T_STEPS - 1);

    // ---- stage ----
    if (r < 10) {
      if (s < T_STEPS)
        stage2<640, 320, 0, 0>(Alds + 2048 * 8,
                               P.hi + (((s - 1) & 1) * 64 + mt * 16) * 320,
                               nullptr, nullptr, tid);
    } else if (r < 17) {
      if (s >= 1 && s <= T_STEPS)
        stage2<640, 320, 448, 224>(Alds, P.hi + (((s - 1) & 1) * 64 + mt * 16) * 320,
                                   Alds + 640 * 8,
                                   P.hc + (((s - 2) & 1) * 64 + mt * 16) * 224, tid);
    } else {
      if (s >= 2)
        stage2<448, 224, 1024, 512>(Alds, P.hc + (((s - 2) & 1) * 64 + mt * 16) * 224,
                                    Alds + 448 * 8,
                                    P.hm + (((s - 3) & 1) * 64 + mt * 16) * 512, tid);
    }
    __syncthreads();                      // (A) LDS staged
    if (tid == 0) stf(rf + r, (unsigned)(s + 1));

    // ---- spans (pair-split) ----
    f32x4 A[4];
#pragma unroll
    for (int j = 0; j < 4; ++j) A[j] = {0.f, 0.f, 0.f, 0.f};
    if (on) {
      if (r < 10) {
        const ushort_t* bp = P.pack + PACK0 + (size_t)nt * 26 * 2048;
        if (role == 0) mfma_span<16>(bp, Alds + (s & 1) * (1024 * 8), lane, A[0], A[1], A[2], A[3]);
        else           mfma_span<10>(bp + 16 * 2048, Alds + 2048 * 8, lane, A[0], A[1], A[2], A[3]);
      } else if (r < 17) {
        const ushort_t* bp = P.pack + PACK1 + (size_t)nt * 17 * 2048;
        if (role == 0) mfma_span<10>(bp, Alds, lane, A[0], A[1], A[2], A[3]);
        else           mfma_span<7>(bp + 10 * 2048, Alds + 640 * 8, lane, A[0], A[1], A[2], A[3]);
      } else {
        const ushort_t* bp = P.pack + PACK2 + (size_t)nt * 23 * 2048;
        if (role == 0) mfma_span<7>(bp, Alds, lane, A[0], A[1], A[2], A[3]);
        else           mfma_span<16>(bp + 7 * 2048, Alds + 448 * 8, lane, A[0], A[1], A[2], A[3]);
      }
      if (role == 1) {
#pragma unroll
        for (int j = 0; j < 4; ++j) pacc[tslot][j * 64 + lane] = A[j];
      }
    }
    __syncthreads();                      // (A2) partner accumulator ready

    // ---- epilogue: h-stores only (y deferred past wf post) ----
    float vk[4];
    if (on && role == 0) {
#pragma unroll
      for (int j = 0; j < 4; ++j) {
        f32x4 p = pacc[tslot][j * 64 + lane];
        A[j][0] += p[0]; A[j][1] += p[1]; A[j][2] += p[2]; A[j][3] += p[3];
      }
      if (r < 10)
        epi_h<308, 320>(A, nt, lane, mt, P.bias[0], P.bias[1], P.bias[2], P.bias[3],
                        P.hi + (tstep & 1) * HI_P, vk);
      else if (r < 17)
        epi_h<204, 224>(A, nt, lane, mt, P.bias[4], P.bias[5], P.bias[6], P.bias[7],
                        P.hc + (tstep & 1) * HC_P, vk);
      else
        epi_h<512, 512>(A, nt, lane, mt, P.bias[8], P.bias[9], P.bias[10], P.bias[11],
                        P.hm + (tstep & 1) * HM_P, vk);
    }
    asm volatile("s_waitcnt vmcnt(0)" ::: "memory");
    __syncthreads();                      // (B) all h stores at coherent point
    if (tid == 0) stf(wf + r, (unsigned)(s + 1));

    // ---- off critical path: deferred y/hfin stores (nontemporal) ----
    if (on && role == 0) {
      const int n_ = nt * 16 + (lane & 15);
      const int r0 = (lane >> 4) << 2;
      const int H_ = (r < 10) ? 308 : ((r < 17) ? 204 : 512);
      const int hoff = (r < 10) ? 0 : ((r < 17) ? 308 : 512);
      if (n_ < H_) {
#pragma unroll
        for (int j = 0; j < 4; ++j) {
          const int brow = mt * 16 + r0 + j;
          if (r >= 17)
            __builtin_nontemporal_store(vk[j], &P.y[((size_t)brow * T_STEPS + tstep) * 512 + n_]);
          if (last)
            __builtin_nontemporal_store(vk[j], &P.hfin[brow * 1024 + hoff + n_]);
        }
      }
    }

    // ---- off critical path: L0 prefetches XN(s+1) into other parity ----
    if (r < 10 && s + 1 < T_STEPS)
      stage_xn(Alds + ((s + 1) & 1) * (1024 * 8), P, mt, tid, s + 1);
  }
}

extern "C" void kernel_launch(void* const* d_in, const int* in_sizes, int n_in,
                              void* d_out, int out_size, void* d_ws, size_t ws_size,
                              hipStream_t stream) {
  const float* x     = (const float*)d_in[27];
  const float* h0    = (const float*)d_in[28];
  const float* gamma = (const float*)d_in[29];
  const float* beta  = (const float*)d_in[30];

  char* ws = (char*)d_ws;
  unsigned* bar = (unsigned*)(ws + WS_BAR);
  float* mu   = (float*)(ws + WS_MU);
  float* rstd = (float*)(ws + WS_RSTD);
  ushort_t* hi = (ushort_t*)(ws + WS_HI);
  ushort_t* hc = (ushort_t*)(ws + WS_HC);
  ushort_t* hm = (ushort_t*)(ws + WS_HM);
  ushort_t* pack = (ushort_t*)(ws + WS_PACK);

  float* y = (float*)d_out;
  float* hfin = y + (size_t)64 * 1024 * 512;

  hipMemsetAsync(bar, 0, 4096, stream);

  ln_stats<<<dim3(16384), dim3(256), 0, stream>>>(x, mu, rstd);
  init_h<<<dim3(264), dim3(256), 0, stream>>>(h0, hi, hc, hm);

  PackP pp;
  for (int l = 0; l < 3; ++l) {
    for (int m = 0; m < 4; ++m) pp.w[l * 4 + m] = (const float*)d_in[l * 9 + 2 * m];
    pp.msk[l] = (const float*)d_in[l * 9 + 8];
  }
  pp.pack = pack;
  ncp_pack<<<dim3(1477), dim3(256), 0, stream>>>(pp);

  MainP mp;
  mp.x = x; mp.gamma = gamma; mp.beta = beta;
  for (int l = 0; l < 3; ++l)
    for (int m = 0; m < 4; ++m) mp.bias[l * 4 + m] = (const float*)d_in[l * 9 + 2 * m + 1];
  mp.mu = mu; mp.rstd = rstd;
  mp.hi = hi; mp.hc = hc; mp.hm = hm;
  mp.pack = pack; mp.bar = bar;
  mp.y = y; mp.hfin = hfin;
  ncp_main<<<dim3(NWG), dim3(256), 0, stream>>>(mp);
}

// Round 13
// 6888.943 us; speedup vs baseline: 2.7949x; 1.3442x over previous
//
#include <hip/hip_runtime.h>

typedef __attribute__((ext_vector_type(8))) short short8;
typedef __attribute__((ext_vector_type(4))) float f32x4;
typedef unsigned short ushort_t;
typedef unsigned long long u64_t;

#define T_STEPS 1024
#define NWG 132
#define NWG_MT 33

// r9/r12 geometry: 33 WGs/mtile, 2 tiles/WG, wave-pair K-split.
//   XN 512 (16 kb) | HI 308->320 (10 kb) | HC 204->224 (7 kb) | HM 512 (16 kb)
// L0: KB=26  NT=20  (10 WGs/mtile, r=0..9)
// L1: KB=17  NT=13  (7 WGs/mtile,  r=10..16)
// L2: KB=23  NT=32  (16 WGs/mtile, r=17..32)
// r13: WEIGHTS IN REGISTERS. Spans rebalanced (L0 13/13, L1 9/8, L2 12/11);
// each wave preloads its span's packed weights (<=13 kb x 4 mats = 208 VGPR)
// once and reuses them for all 1024 slots -> kb-loop is pure LDS+MFMA, zero
// steady-state B traffic. __launch_bounds__(256,1) allows the VGPR budget.
// Everything else (dataflow flags, sc1 exchange, deferred y) = r12.

#define PACK0 0
#define PACK1 1064960            // 20*26*2048
#define PACK2 1517568            // PACK1 + 13*17*2048

#define HI_P (64*320)
#define HC_P (64*224)
#define HM_P (64*512)

// ws offsets (bytes)
#define WS_BAR   0
#define WS_MU    4096
#define WS_RSTD  266240
#define WS_HI    528384
#define WS_HC    610304
#define WS_HM    667648
#define WS_PACK  798720

__device__ __forceinline__ ushort_t f2bf(float f) {
  union { float f; unsigned u; } un; un.f = f;
  unsigned r = (un.u + 0x7fffu + ((un.u >> 16) & 1u)) >> 16;
  return (ushort_t)r;
}

__device__ __forceinline__ void st2(ushort_t* p, ushort_t v) {
  __hip_atomic_store(p, v, __ATOMIC_RELAXED, __HIP_MEMORY_SCOPE_SYSTEM);
}
__device__ __forceinline__ u64_t ld8(const ushort_t* p) {
  return __hip_atomic_load((const u64_t*)p, __ATOMIC_RELAXED, __HIP_MEMORY_SCOPE_SYSTEM);
}
__device__ __forceinline__ unsigned ldf(const unsigned* p) {
  return __hip_atomic_load(p, __ATOMIC_RELAXED, __HIP_MEMORY_SCOPE_SYSTEM);
}
__device__ __forceinline__ void stf(unsigned* p, unsigned v) {
  __hip_atomic_store(p, v, __ATOMIC_RELAXED, __HIP_MEMORY_SCOPE_SYSTEM);
}

// ---------------- LayerNorm stats ----------------
__global__ __launch_bounds__(256) void ln_stats(const float* __restrict__ x,
                                                float* __restrict__ mu,
                                                float* __restrict__ rstd) {
  const int row = blockIdx.x * 4 + (threadIdx.x >> 6);
  const int lane = threadIdx.x & 63;
  const float* xr = x + (size_t)row * 512;
  float4 v0 = *(const float4*)(xr + lane * 8);
  float4 v1 = *(const float4*)(xr + lane * 8 + 4);
  float s = v0.x + v0.y + v0.z + v0.w + v1.x + v1.y + v1.z + v1.w;
  float q = v0.x*v0.x + v0.y*v0.y + v0.z*v0.z + v0.w*v0.w
          + v1.x*v1.x + v1.y*v1.y + v1.z*v1.z + v1.w*v1.w;
  for (int m = 1; m <= 32; m <<= 1) {
    s += __shfl_xor(s, m, 64);
    q += __shfl_xor(q, m, 64);
  }
  if (lane == 0) {
    float mean = s * (1.f / 512.f);
    float var = q * (1.f / 512.f) - mean * mean;
    mu[row] = mean;
    rstd[row] = rsqrtf(var + 1e-5f);
  }
}

// ---------------- init hidden state: bf16 linear padded, BOTH parities -------
__global__ void init_h(const float* __restrict__ h0,
                       ushort_t* hi, ushort_t* hc, ushort_t* hm) {
  int i = blockIdx.x * 256 + threadIdx.x;
  if (i >= 64 * 1056) return;
  int b = i / 1056, c = i % 1056;
  if (c < 320) {
    ushort_t v = (c < 308) ? f2bf(h0[b * 1024 + c]) : 0;
    st2(hi + b * 320 + c, v); st2(hi + HI_P + b * 320 + c, v);
  } else if (c < 544) {
    int col = c - 320;
    ushort_t v = (col < 204) ? f2bf(h0[b * 1024 + 308 + col]) : 0;
    st2(hc + b * 224 + col, v); st2(hc + HC_P + b * 224 + col, v);
  } else {
    int col = c - 544;
    ushort_t v = f2bf(h0[b * 1024 + 512 + col]);
    st2(hm + b * 512 + col, v); st2(hm + HM_P + b * 512 + col, v);
  }
}

// ---------------- pack masked weights ----------------
struct PackP {
  const float* w[12];
  const float* msk[3];
  ushort_t* pack;
};

__global__ __launch_bounds__(256) void ncp_pack(PackP P) {
  int u = blockIdx.x * 256 + threadIdx.x;
  int layer, rem, KB, K, H, s0p, s0l, s1l;
  size_t base;
  if (u < 133120)      { layer = 0; rem = u;          KB = 26; K = 820; H = 308; s0p = 512; s0l = 512; s1l = 308; base = PACK0; }
  else if (u < 189696) { layer = 1; rem = u - 133120; KB = 17; K = 512; H = 204; s0p = 320; s0l = 308; s1l = 204; base = PACK1; }
  else if (u < 378112) { layer = 2; rem = u - 189696; KB = 23; K = 716; H = 512; s0p = 224; s0l = 204; s1l = 512; base = PACK2; }
  else return;
  const int lane = rem & 63;
  const int mat = (rem >> 6) & 3;
  const int kb = (rem >> 8) % KB;
  const int nt = (rem >> 8) / KB;
  const float* W = P.w[layer * 4 + mat];
  const float* M = (mat < 2) ? P.msk[layer] : nullptr;
  const int n = nt * 16 + (lane & 15);
  const int kbase = kb * 32 + ((lane >> 4) << 3);
  ushort_t* dst = P.pack + base + (size_t)rem * 8;
#pragma unroll
  for (int j = 0; j < 8; ++j) {
    const int kp = kbase + j;
    int ko;
    if (kp < s0p) ko = (kp < s0l) ? kp : -1;
    else { const int ks = kp - s0p; ko = (ks < s1l) ? (s0l + ks) : -1; }
    float v = 0.f;
    if (n < H && ko >= 0) {
      v = W[(size_t)n * K + ko];
      if (M) v *= M[(size_t)n * K + ko];
    }
    dst[j] = f2bf(v);
  }
}

// ---------------- main persistent kernel ----------------
struct MainP {
  const float* x;
  const float* gamma;
  const float* beta;
  const float* bias[12];
  const float* mu;
  const float* rstd;
  ushort_t* hi;
  ushort_t* hc;
  ushort_t* hm;
  const ushort_t* pack;
  unsigned* bar;
  float* y;
  float* hfin;
};

#define MAXKB 13

// one-time load of a span's weights into registers (compile-time indices only)
template<int KBT>
__device__ __forceinline__ void load_w(const ushort_t* __restrict__ bp, int lane,
                                       short8 (*w)[4]) {
#pragma unroll
  for (int kb = 0; kb < KBT; ++kb) {
    const ushort_t* q = bp + (size_t)kb * 2048 + lane * 8;
    w[kb][0] = *(const short8*)(q);
    w[kb][1] = *(const short8*)(q + 512);
    w[kb][2] = *(const short8*)(q + 1024);
    w[kb][3] = *(const short8*)(q + 1536);
  }
}

// register-resident-weight MFMA span: pure LDS-read + MFMA
template<int KBT>
__device__ __forceinline__ void span_reg(const short8 (*w)[4],
                                         const ushort_t* __restrict__ lds, int lane,
                                         f32x4& a0, f32x4& a1, f32x4& a2, f32x4& a3) {
#pragma unroll
  for (int kb = 0; kb < KBT; ++kb) {
    short8 av = *(const short8*)(lds + (size_t)(kb * 64 + lane) * 8);
    a0 = __builtin_amdgcn_mfma_f32_16x16x32_bf16(av, w[kb][0], a0, 0, 0, 0);
    a1 = __builtin_amdgcn_mfma_f32_16x16x32_bf16(av, w[kb][1], a1, 0, 0, 0);
    a2 = __builtin_amdgcn_mfma_f32_16x16x32_bf16(av, w[kb][2], a2, 0, 0, 0);
    a3 = __builtin_amdgcn_mfma_f32_16x16x32_bf16(av, w[kb][3], a3, 0, 0, 0);
  }
}

// h-only epilogue: apply gates, store h (st2), keep v in regs for deferred y.
template<int H, int STP>
__device__ __forceinline__ void epi_h(const f32x4* A, int nt, int lane, int mtile,
                                      const float* __restrict__ bp1, const float* __restrict__ bp2,
                                      const float* __restrict__ bpa, const float* __restrict__ bpb,
                                      ushort_t* __restrict__ hout, float* vk) {
  const int n = nt * 16 + (lane & 15);
  const int r0 = (lane >> 4) << 2;
#pragma unroll
  for (int j = 0; j < 4; ++j) vk[j] = 0.f;
  if (n < H) {
    float c1 = bp1[n], c2 = bp2[n], ca = bpa[n], cb = bpb[n];
#pragma unroll
    for (int j = 0; j < 4; ++j) {
      int brow = mtile * 16 + r0 + j;
      float sg = 1.f / (1.f + __expf(-(A[2][j] + ca + A[3][j] + cb)));
      float f1 = 1.f - 2.f / (1.f + __expf(2.f * (A[0][j] + c1)));
      float f2 = 1.f - 2.f / (1.f + __expf(2.f * (A[1][j] + c2)));
      float v = f1 * (1.f - sg) + sg * f2;
      vk[j] = v;
      st2(hout + (size_t)brow * STP + n, f2bf(v));
    }
  }
}

// stage up to two bf16 padded segments; coalesced 8B units, all loads issued
// before any LDS write -> ~1 coherent-point round trip.
template<int S1, int ST1, int S2, int ST2>
__device__ __forceinline__ void stage2(ushort_t* __restrict__ r1, const ushort_t* __restrict__ h1,
                                       ushort_t* __restrict__ r2, const ushort_t* __restrict__ h2,
                                       int tid) {
  constexpr int U1 = S1 * 2, U2 = S2 * 2;
  constexpr int I1 = (U1 + 255) / 256;
  constexpr int I2 = (U2 + 255) / 256;
  u64_t a[I1];
  u64_t b[I2 > 0 ? I2 : 1];
#pragma unroll
  for (int i = 0; i < I1; ++i) {
    const int u = tid + i * 256;
    if ((U1 & 255) == 0 || u < U1) {
      const int slot = u >> 1;
      a[i] = ld8(h1 + (slot & 15) * ST1 + (slot >> 6) * 32 + ((slot >> 4) & 3) * 8 + (u & 1) * 4);
    }
  }
  if constexpr (S2 > 0) {
#pragma unroll
    for (int i = 0; i < I2; ++i) {
      const int u = tid + i * 256;
      if ((U2 & 255) == 0 || u < U2) {
        const int slot = u >> 1;
        b[i] = ld8(h2 + (slot & 15) * ST2 + (slot >> 6) * 32 + ((slot >> 4) & 3) * 8 + (u & 1) * 4);
      }
    }
  }
#pragma unroll
  for (int i = 0; i < I1; ++i) {
    const int u = tid + i * 256;
    if ((U1 & 255) == 0 || u < U1) *(u64_t*)(r1 + (size_t)u * 4) = a[i];
  }
  if constexpr (S2 > 0) {
#pragma unroll
    for (int i = 0; i < I2; ++i) {
      const int u = tid + i * 256;
      if ((U2 & 255) == 0 || u < U2) *(u64_t*)(r2 + (size_t)u * 4) = b[i];
    }
  }
}

__device__ __forceinline__ void stage_xn(ushort_t* __restrict__ XN, const MainP& P,
                                         int mtile, int tid, int t) {
#pragma unroll
  for (int i = 0; i < 4; ++i) {
    const int s = tid + i * 256;
    const int ln = s & 63;
    const int brow = mtile * 16 + (ln & 15);
    const int kbase = (s >> 6) * 32 + ((ln >> 4) << 3);
    const float muv = P.mu[brow * T_STEPS + t];
    const float rsv = P.rstd[brow * T_STEPS + t];
    const f32x4* xr = (const f32x4*)(P.x + ((size_t)brow * T_STEPS + t) * 512 + kbase);
    f32x4 xv0 = __builtin_nontemporal_load(xr);
    f32x4 xv1 = __builtin_nontemporal_load(xr + 1);
    const f32x4 g0 = *(const f32x4*)(P.gamma + kbase);
    const f32x4 g1 = *(const f32x4*)(P.gamma + kbase + 4);
    const f32x4 b0 = *(const f32x4*)(P.beta + kbase);
    const f32x4 b1 = *(const f32x4*)(P.beta + kbase + 4);
    short8 w;
#pragma unroll
    for (int j = 0; j < 4; ++j) w[j] = f2bf((xv0[j] - muv) * rsv * g0[j] + b0[j]);
#pragma unroll
    for (int j = 0; j < 4; ++j) w[4 + j] = f2bf((xv1[j] - muv) * rsv * g1[j] + b1[j]);
    *(short8*)(XN + (size_t)s * 8) = w;
  }
}

__global__ __launch_bounds__(256, 1) void ncp_main(MainP P) {
  const int tid = threadIdx.x;
  const int lane = tid & 63;
  const int wv = tid >> 6;
  const int role = wv & 1;        // span half within the tile
  const int tslot = wv >> 1;      // which of the WG's 2 tiles
  const int wg = blockIdx.x;
  const int mt = wg / NWG_MT;     // 0..3
  const int r  = wg % NWG_MT;     // 0..9: L0, 10..16: L1, 17..32: L2

  __shared__ __align__(16) ushort_t Alds[2688 * 8];  // 42 KB staging (L0 layout)
  __shared__ __align__(16) f32x4 pacc[2][256];       // 8 KB partials (dense)
  // L0: XN parity0 [0..1023], XN parity1 [1024..2047], HI [2048..2687]
  // L1: HI [0..639], HC [640..1087]
  // L2: HC [0..447], HM [448..1471]

  // ---- dataflow-flag setup (r9 protocol) ----
  unsigned* wf = P.bar + mt * 128;       // wflag[0..32]
  unsigned* rf = wf + 64;                // rflag[0..32]
  int wa, wb, ra, rb;
  if (r < 10)      { wa = 0;  wb = 10; ra = 0;  rb = 17; }
  else if (r < 17) { wa = 0;  wb = 17; ra = 10; rb = 33; }
  else             { wa = 10; wb = 33; ra = 17; rb = 33; }
  const int nw = wb - wa, nr = rb - ra;
  const unsigned* paddr = wf;
  bool pact = false;
  if (lane < nw)           { paddr = wf + wa + lane;        pact = true; }
  else if (lane < nw + nr) { paddr = rf + ra + (lane - nw); pact = true; }

  // ---- per-wave tile/validity ----
  int nt = 0;
  bool valid = true;
  if (r < 10)      nt = r * 2 + tslot;
  else if (r < 17) { nt = (r - 10) * 2 + tslot; valid = (nt < 13); }
  else             nt = (r - 17) * 2 + tslot;

  // ---- one-time weight preload into registers ----
  // K-order kbs per tile: L0: [0,16)=XN [16,26)=HI ; spans role0=[0,13) role1=[13,26)
  //                       L1: [0,10)=HI [10,17)=HC ; spans [0,9) / [9,17)
  //                       L2: [0,7)=HC  [7,23)=HM  ; spans [0,12) / [12,23)
  short8 wreg[MAXKB][4];
  if (valid) {
    if (r < 10) {
      const ushort_t* bp = P.pack + PACK0 + (size_t)nt * 26 * 2048 + (role ? 13 : 0) * 2048;
      load_w<13>(bp, lane, wreg);
    } else if (r < 17) {
      const ushort_t* bp = P.pack + PACK1 + (size_t)nt * 17 * 2048;
      if (role == 0) load_w<9>(bp, lane, wreg);
      else           load_w<8>(bp + 9 * 2048, lane, wreg);
    } else {
      const ushort_t* bp = P.pack + PACK2 + (size_t)nt * 23 * 2048;
      if (role == 0) load_w<12>(bp, lane, wreg);
      else           load_w<11>(bp + 12 * 2048, lane, wreg);
    }
  }

  if (r < 10) stage_xn(Alds, P, mt, tid, 0);  // prologue XN(0) into parity-0

  for (int s = 0; s < T_STEPS + 2; ++s) {
    // ---- wait ----
    if (wv == 0) {
      const unsigned need = (unsigned)s;
      for (;;) {
        unsigned v = pact ? ldf(paddr) : 0xFFFFFFFFu;
        if (__all((int)(v >= need))) break;
      }
    }
    __syncthreads();

    // ---- per-layer slot state ----
    int tstep = 0;
    bool on = false;
    if (r < 10)      { tstep = s;     on = (s < T_STEPS); }
    else if (r < 17) { tstep = s - 1; on = (s >= 1 && s <= T_STEPS) && valid; }
    else             { tstep = s - 2; on = (s >= 2); }
    const bool last = (tstep == T_STEPS - 1);

    // ---- stage ----
    if (r < 10) {
      if (s < T_STEPS)
        stage2<640, 320, 0, 0>(Alds + 2048 * 8,
                               P.hi + (((s - 1) & 1) * 64 + mt * 16) * 320,
                               nullptr, nullptr, tid);
    } else if (r < 17) {
      if (s >= 1 && s <= T_STEPS)
        stage2<640, 320, 448, 224>(Alds, P.hi + (((s - 1) & 1) * 64 + mt * 16) * 320,
                                   Alds + 640 * 8,
                                   P.hc + (((s - 2) & 1) * 64 + mt * 16) * 224, tid);
    } else {
      if (s >= 2)
        stage2<448, 224, 1024, 512>(Alds, P.hc + (((s - 2) & 1) * 64 + mt * 16) * 224,
                                    Alds + 448 * 8,
                                    P.hm + (((s - 3) & 1) * 64 + mt * 16) * 512, tid);
    }
    __syncthreads();                      // (A) LDS staged
    if (tid == 0) stf(rf + r, (unsigned)(s + 1));

    // ---- spans (register-resident weights; pure LDS+MFMA) ----
    f32x4 A[4];
#pragma unroll
    for (int j = 0; j < 4; ++j) A[j] = {0.f, 0.f, 0.f, 0.f};
    if (on) {
      if (r < 10) {
        const ushort_t* XNc = Alds + (s & 1) * (1024 * 8);
        const ushort_t* HIl = Alds + 2048 * 8;
        if (role == 0) span_reg<13>(wreg, XNc, lane, A[0], A[1], A[2], A[3]);
        else { span_reg<3>(wreg, XNc + 13 * 512, lane, A[0], A[1], A[2], A[3]);
               span_reg<10>(wreg + 3, HIl, lane, A[0], A[1], A[2], A[3]); }
      } else if (r < 17) {
        const ushort_t* HIr = Alds;
        const ushort_t* HCr = Alds + 640 * 8;
        if (role == 0) span_reg<9>(wreg, HIr, lane, A[0], A[1], A[2], A[3]);
        else { span_reg<1>(wreg, HIr + 9 * 512, lane, A[0], A[1], A[2], A[3]);
               span_reg<7>(wreg + 1, HCr, lane, A[0], A[1], A[2], A[3]); }
      } else {
        const ushort_t* HCr = Alds;
        const ushort_t* HMr = Alds + 448 * 8;
        if (role == 0) { span_reg<7>(wreg, HCr, lane, A[0], A[1], A[2], A[3]);
                         span_reg<5>(wreg + 7, HMr, lane, A[0], A[1], A[2], A[3]); }
        else           span_reg<11>(wreg, HMr + 5 * 512, lane, A[0], A[1], A[2], A[3]);
      }
      if (role == 1) {
#pragma unroll
        for (int j = 0; j < 4; ++j) pacc[tslot][j * 64 + lane] = A[j];
      }
    }
    __syncthreads();                      // (A2) partner accumulator ready

    // ---- epilogue: h-stores only (y deferred past wf post) ----
    float vk[4];
    if (on && role == 0) {
#pragma unroll
      for (int j = 0; j < 4; ++j) {
        f32x4 p = pacc[tslot][j * 64 + lane];
        A[j][0] += p[0]; A[j][1] += p[1]; A[j][2] += p[2]; A[j][3] += p[3];
      }
      if (r < 10)
        epi_h<308, 320>(A, nt, lane, mt, P.bias[0], P.bias[1], P.bias[2], P.bias[3],
                        P.hi + (tstep & 1) * HI_P, vk);
      else if (r < 17)
        epi_h<204, 224>(A, nt, lane, mt, P.bias[4], P.bias[5], P.bias[6], P.bias[7],
                        P.hc + (tstep & 1) * HC_P, vk);
      else
        epi_h<512, 512>(A, nt, lane, mt, P.bias[8], P.bias[9], P.bias[10], P.bias[11],
                        P.hm + (tstep & 1) * HM_P, vk);
    }
    asm volatile("s_waitcnt vmcnt(0)" ::: "memory");
    __syncthreads();                      // (B) all h stores at coherent point
    if (tid == 0) stf(wf + r, (unsigned)(s + 1));

    // ---- off critical path: deferred y/hfin stores (nontemporal) ----
    if (on && role == 0) {
      const int n_ = nt * 16 + (lane & 15);
      const int r0 = (lane >> 4) << 2;
      const int H_ = (r < 10) ? 308 : ((r < 17) ? 204 : 512);
      const int hoff = (r < 10) ? 0 : ((r < 17) ? 308 : 512);
      if (n_ < H_) {
#pragma unroll
        for (int j = 0; j < 4; ++j) {
          const int brow = mt * 16 + r0 + j;
          if (r >= 17)
            __builtin_nontemporal_store(vk[j], &P.y[((size_t)brow * T_STEPS + tstep) * 512 + n_]);
          if (last)
            __builtin_nontemporal_store(vk[j], &P.hfin[brow * 1024 + hoff + n_]);
        }
      }
    }

    // ---- off critical path: L0 prefetches XN(s+1) into other parity ----
    if (r < 10 && s + 1 < T_STEPS)
      stage_xn(Alds + ((s + 1) & 1) * (1024 * 8), P, mt, tid, s + 1);
  }
}

extern "C" void kernel_launch(void* const* d_in, const int* in_sizes, int n_in,
                              void* d_out, int out_size, void* d_ws, size_t ws_size,
                              hipStream_t stream) {
  const float* x     = (const float*)d_in[27];
  const float* h0    = (const float*)d_in[28];
  const float* gamma = (const float*)d_in[29];
  const float* beta  = (const float*)d_in[30];

  char* ws = (char*)d_ws;
  unsigned* bar = (unsigned*)(ws + WS_BAR);
  float* mu   = (float*)(ws + WS_MU);
  float* rstd = (float*)(ws + WS_RSTD);
  ushort_t* hi = (ushort_t*)(ws + WS_HI);
  ushort_t* hc = (ushort_t*)(ws + WS_HC);
  ushort_t* hm = (ushort_t*)(ws + WS_HM);
  ushort_t* pack = (ushort_t*)(ws + WS_PACK);

  float* y = (float*)d_out;
  float* hfin = y + (size_t)64 * 1024 * 512;

  hipMemsetAsync(bar, 0, 4096, stream);

  ln_stats<<<dim3(16384), dim3(256), 0, stream>>>(x, mu, rstd);
  init_h<<<dim3(264), dim3(256), 0, stream>>>(h0, hi, hc, hm);

  PackP pp;
  for (int l = 0; l < 3; ++l) {
    for (int m = 0; m < 4; ++m) pp.w[l * 4 + m] = (const float*)d_in[l * 9 + 2 * m];
    pp.msk[l] = (const float*)d_in[l * 9 + 8];
  }
  pp.pack = pack;
  ncp_pack<<<dim3(1477), dim3(256), 0, stream>>>(pp);

  MainP mp;
  mp.x = x; mp.gamma = gamma; mp.beta = beta;
  for (int l = 0; l < 3; ++l)
    for (int m = 0; m < 4; ++m) mp.bias[l * 4 + m] = (const float*)d_in[l * 9 + 2 * m + 1];
  mp.mu = mu; mp.rstd = rstd;
  mp.hi = hi; mp.hc = hc; mp.hm = hm;
  mp.pack = pack; mp.bar = bar;
  mp.y = y; mp.hfin = hfin;
  ncp_main<<<dim3(NWG), dim3(256), 0, stream>>>(mp);
}

// Round 14
// 6730.421 us; speedup vs baseline: 2.8607x; 1.0236x over previous
//
#include <hip/hip_runtime.h>

typedef __attribute__((ext_vector_type(8))) short short8;
typedef __attribute__((ext_vector_type(4))) float f32x4;
typedef unsigned short ushort_t;
typedef unsigned long long u64_t;

#define T_STEPS 1024
#define NWG 132
#define NWG_MT 33

// r13 structure (weights-in-registers, 33 WGs/mtile, 2 tiles/WG, wave-pair
// K-split). r14: slimmed sync protocol:
//  - rf flags REMOVED. WAR guard = readers' wf >= s (wf posted at end of slot
//    s-1 after staging+compute+drain, so wf>=s  =>  slot-(s-1) reads done).
//  - pre-wait (before stage), producers only:  L0 wf[0,10)  L1 wf[0,17)
//    L2 wf[10,33).
//  - mid-wait (writer waves only, before h-write; hides under compute):
//    L0 wf[10,17) (L1 reads hi); L1 wf[17,33) (L2 reads hc); L2 none
//    (hm readers [17,33) subset of its pre-wait [10,33)).
//  - flags spread 1/64B line (wf[r*16], mtile stride 4KB); s_sleep(1) backoff.
// RAW/WAR audit: hi(s) wr by L0@s after pre[0,10)+mid[10,17)>=s covers readers
// of hi(s-2)@slot s-1 (L0 stage, L1 stage). hc(s-1) wr by L1@s: own order +
// pre[0,17) + mid[17,33)>=s covers L1/L2 reads of hc(s-3)@s-1. hm(s-2) wr by
// L2@s: readers L2 only, pre[10,33)>=s covers. RAW all covered by pre-waits.

#define PACK0 0
#define PACK1 1064960            // 20*26*2048
#define PACK2 1517568            // PACK1 + 13*17*2048

#define HI_P (64*320)
#define HC_P (64*224)
#define HM_P (64*512)

// ws offsets (bytes)
#define WS_BAR   0               // 4 mtiles x 4KB of spread flags
#define WS_MU    16384
#define WS_RSTD  278528
#define WS_HI    540672
#define WS_HC    622592
#define WS_HM    679936
#define WS_PACK  811008          // + 6049792 -> ends 6860800

__device__ __forceinline__ ushort_t f2bf(float f) {
  union { float f; unsigned u; } un; un.f = f;
  unsigned r = (un.u + 0x7fffu + ((un.u >> 16) & 1u)) >> 16;
  return (ushort_t)r;
}

__device__ __forceinline__ void st2(ushort_t* p, ushort_t v) {
  __hip_atomic_store(p, v, __ATOMIC_RELAXED, __HIP_MEMORY_SCOPE_SYSTEM);
}
__device__ __forceinline__ u64_t ld8(const ushort_t* p) {
  return __hip_atomic_load((const u64_t*)p, __ATOMIC_RELAXED, __HIP_MEMORY_SCOPE_SYSTEM);
}
__device__ __forceinline__ unsigned ldf(const unsigned* p) {
  return __hip_atomic_load(p, __ATOMIC_RELAXED, __HIP_MEMORY_SCOPE_SYSTEM);
}
__device__ __forceinline__ void stf(unsigned* p, unsigned v) {
  __hip_atomic_store(p, v, __ATOMIC_RELAXED, __HIP_MEMORY_SCOPE_SYSTEM);
}

// ---------------- LayerNorm stats ----------------
__global__ __launch_bounds__(256) void ln_stats(const float* __restrict__ x,
                                                float* __restrict__ mu,
                                                float* __restrict__ rstd) {
  const int row = blockIdx.x * 4 + (threadIdx.x >> 6);
  const int lane = threadIdx.x & 63;
  const float* xr = x + (size_t)row * 512;
  float4 v0 = *(const float4*)(xr + lane * 8);
  float4 v1 = *(const float4*)(xr + lane * 8 + 4);
  float s = v0.x + v0.y + v0.z + v0.w + v1.x + v1.y + v1.z + v1.w;
  float q = v0.x*v0.x + v0.y*v0.y + v0.z*v0.z + v0.w*v0.w
          + v1.x*v1.x + v1.y*v1.y + v1.z*v1.z + v1.w*v1.w;
  for (int m = 1; m <= 32; m <<= 1) {
    s += __shfl_xor(s, m, 64);
    q += __shfl_xor(q, m, 64);
  }
  if (lane == 0) {
    float mean = s * (1.f / 512.f);
    float var = q * (1.f / 512.f) - mean * mean;
    mu[row] = mean;
    rstd[row] = rsqrtf(var + 1e-5f);
  }
}

// ---------------- init hidden state: bf16 linear padded, BOTH parities -------
__global__ void init_h(const float* __restrict__ h0,
                       ushort_t* hi, ushort_t* hc, ushort_t* hm) {
  int i = blockIdx.x * 256 + threadIdx.x;
  if (i >= 64 * 1056) return;
  int b = i / 1056, c = i % 1056;
  if (c < 320) {
    ushort_t v = (c < 308) ? f2bf(h0[b * 1024 + c]) : 0;
    st2(hi + b * 320 + c, v); st2(hi + HI_P + b * 320 + c, v);
  } else if (c < 544) {
    int col = c - 320;
    ushort_t v = (col < 204) ? f2bf(h0[b * 1024 + 308 + col]) : 0;
    st2(hc + b * 224 + col, v); st2(hc + HC_P + b * 224 + col, v);
  } else {
    int col = c - 544;
    ushort_t v = f2bf(h0[b * 1024 + 512 + col]);
    st2(hm + b * 512 + col, v); st2(hm + HM_P + b * 512 + col, v);
  }
}

// ---------------- pack masked weights ----------------
struct PackP {
  const float* w[12];
  const float* msk[3];
  ushort_t* pack;
};

__global__ __launch_bounds__(256) void ncp_pack(PackP P) {
  int u = blockIdx.x * 256 + threadIdx.x;
  int layer, rem, KB, K, H, s0p, s0l, s1l;
  size_t base;
  if (u < 133120)      { layer = 0; rem = u;          KB = 26; K = 820; H = 308; s0p = 512; s0l = 512; s1l = 308; base = PACK0; }
  else if (u < 189696) { layer = 1; rem = u - 133120; KB = 17; K = 512; H = 204; s0p = 320; s0l = 308; s1l = 204; base = PACK1; }
  else if (u < 378112) { layer = 2; rem = u - 189696; KB = 23; K = 716; H = 512; s0p = 224; s0l = 204; s1l = 512; base = PACK2; }
  else return;
  const int lane = rem & 63;
  const int mat = (rem >> 6) & 3;
  const int kb = (rem >> 8) % KB;
  const int nt = (rem >> 8) / KB;
  const float* W = P.w[layer * 4 + mat];
  const float* M = (mat < 2) ? P.msk[layer] : nullptr;
  const int n = nt * 16 + (lane & 15);
  const int kbase = kb * 32 + ((lane >> 4) << 3);
  ushort_t* dst = P.pack + base + (size_t)rem * 8;
#pragma unroll
  for (int j = 0; j < 8; ++j) {
    const int kp = kbase + j;
    int ko;
    if (kp < s0p) ko = (kp < s0l) ? kp : -1;
    else { const int ks = kp - s0p; ko = (ks < s1l) ? (s0l + ks) : -1; }
    float v = 0.f;
    if (n < H && ko >= 0) {
      v = W[(size_t)n * K + ko];
      if (M) v *= M[(size_t)n * K + ko];
    }
    dst[j] = f2bf(v);
  }
}

// ---------------- main persistent kernel ----------------
struct MainP {
  const float* x;
  const float* gamma;
  const float* beta;
  const float* bias[12];
  const float* mu;
  const float* rstd;
  ushort_t* hi;
  ushort_t* hc;
  ushort_t* hm;
  const ushort_t* pack;
  unsigned* bar;
  float* y;
  float* hfin;
};

#define MAXKB 13

template<int KBT>
__device__ __forceinline__ void load_w(const ushort_t* __restrict__ bp, int lane,
                                       short8 (*w)[4]) {
#pragma unroll
  for (int kb = 0; kb < KBT; ++kb) {
    const ushort_t* q = bp + (size_t)kb * 2048 + lane * 8;
    w[kb][0] = *(const short8*)(q);
    w[kb][1] = *(const short8*)(q + 512);
    w[kb][2] = *(const short8*)(q + 1024);
    w[kb][3] = *(const short8*)(q + 1536);
  }
}

template<int KBT>
__device__ __forceinline__ void span_reg(const short8 (*w)[4],
                                         const ushort_t* __restrict__ lds, int lane,
                                         f32x4& a0, f32x4& a1, f32x4& a2, f32x4& a3) {
#pragma unroll
  for (int kb = 0; kb < KBT; ++kb) {
    short8 av = *(const short8*)(lds + (size_t)(kb * 64 + lane) * 8);
    a0 = __builtin_amdgcn_mfma_f32_16x16x32_bf16(av, w[kb][0], a0, 0, 0, 0);
    a1 = __builtin_amdgcn_mfma_f32_16x16x32_bf16(av, w[kb][1], a1, 0, 0, 0);
    a2 = __builtin_amdgcn_mfma_f32_16x16x32_bf16(av, w[kb][2], a2, 0, 0, 0);
    a3 = __builtin_amdgcn_mfma_f32_16x16x32_bf16(av, w[kb][3], a3, 0, 0, 0);
  }
}

template<int H, int STP>
__device__ __forceinline__ void epi_h(const f32x4* A, int nt, int lane, int mtile,
                                      const float* __restrict__ bp1, const float* __restrict__ bp2,
                                      const float* __restrict__ bpa, const float* __restrict__ bpb,
                                      ushort_t* __restrict__ hout, float* vk) {
  const int n = nt * 16 + (lane & 15);
  const int r0 = (lane >> 4) << 2;
#pragma unroll
  for (int j = 0; j < 4; ++j) vk[j] = 0.f;
  if (n < H) {
    float c1 = bp1[n], c2 = bp2[n], ca = bpa[n], cb = bpb[n];
#pragma unroll
    for (int j = 0; j < 4; ++j) {
      int brow = mtile * 16 + r0 + j;
      float sg = 1.f / (1.f + __expf(-(A[2][j] + ca + A[3][j] + cb)));
      float f1 = 1.f - 2.f / (1.f + __expf(2.f * (A[0][j] + c1)));
      float f2 = 1.f - 2.f / (1.f + __expf(2.f * (A[1][j] + c2)));
      float v = f1 * (1.f - sg) + sg * f2;
      vk[j] = v;
      st2(hout + (size_t)brow * STP + n, f2bf(v));
    }
  }
}

template<int S1, int ST1, int S2, int ST2>
__device__ __forceinline__ void stage2(ushort_t* __restrict__ r1, const ushort_t* __restrict__ h1,
                                       ushort_t* __restrict__ r2, const ushort_t* __restrict__ h2,
                                       int tid) {
  constexpr int U1 = S1 * 2, U2 = S2 * 2;
  constexpr int I1 = (U1 + 255) / 256;
  constexpr int I2 = (U2 + 255) / 256;
  u64_t a[I1];
  u64_t b[I2 > 0 ? I2 : 1];
#pragma unroll
  for (int i = 0; i < I1; ++i) {
    const int u = tid + i * 256;
    if ((U1 & 255) == 0 || u < U1) {
      const int slot = u >> 1;
      a[i] = ld8(h1 + (slot & 15) * ST1 + (slot >> 6) * 32 + ((slot >> 4) & 3) * 8 + (u & 1) * 4);
    }
  }
  if constexpr (S2 > 0) {
#pragma unroll
    for (int i = 0; i < I2; ++i) {
      const int u = tid + i * 256;
      if ((U2 & 255) == 0 || u < U2) {
        const int slot = u >> 1;
        b[i] = ld8(h2 + (slot & 15) * ST2 + (slot >> 6) * 32 + ((slot >> 4) & 3) * 8 + (u & 1) * 4);
      }
    }
  }
#pragma unroll
  for (int i = 0; i < I1; ++i) {
    const int u = tid + i * 256;
    if ((U1 & 255) == 0 || u < U1) *(u64_t*)(r1 + (size_t)u * 4) = a[i];
  }
  if constexpr (S2 > 0) {
#pragma unroll
    for (int i = 0; i < I2; ++i) {
      const int u = tid + i * 256;
      if ((U2 & 255) == 0 || u < U2) *(u64_t*)(r2 + (size_t)u * 4) = b[i];
    }
  }
}

__device__ __forceinline__ void stage_xn(ushort_t* __restrict__ XN, const MainP& P,
                                         int mtile, int tid, int t) {
#pragma unroll
  for (int i = 0; i < 4; ++i) {
    const int s = tid + i * 256;
    const int ln = s & 63;
    const int brow = mtile * 16 + (ln & 15);
    const int kbase = (s >> 6) * 32 + ((ln >> 4) << 3);
    const float muv = P.mu[brow * T_STEPS + t];
    const float rsv = P.rstd[brow * T_STEPS + t];
    const f32x4* xr = (const f32x4*)(P.x + ((size_t)brow * T_STEPS + t) * 512 + kbase);
    f32x4 xv0 = __builtin_nontemporal_load(xr);
    f32x4 xv1 = __builtin_nontemporal_load(xr + 1);
    const f32x4 g0 = *(const f32x4*)(P.gamma + kbase);
    const f32x4 g1 = *(const f32x4*)(P.gamma + kbase + 4);
    const f32x4 b0 = *(const f32x4*)(P.beta + kbase);
    const f32x4 b1 = *(const f32x4*)(P.beta + kbase + 4);
    short8 w;
#pragma unroll
    for (int j = 0; j < 4; ++j) w[j] = f2bf((xv0[j] - muv) * rsv * g0[j] + b0[j]);
#pragma unroll
    for (int j = 0; j < 4; ++j) w[4 + j] = f2bf((xv1[j] - muv) * rsv * g1[j] + b1[j]);
    *(short8*)(XN + (size_t)s * 8) = w;
  }
}

// wave-level poll: lanes [0,cnt) each watch one spread flag; backoff s_sleep(1)
__device__ __forceinline__ void poll_wf(const unsigned* wfbase, int a, int cnt,
                                        int lane, unsigned need) {
  const unsigned* p = wfbase + (a + (lane < cnt ? lane : 0)) * 16;
  const bool act = lane < cnt;
  for (;;) {
    unsigned v = act ? ldf(p) : 0xFFFFFFFFu;
    if (__all((int)(v >= need))) break;
    __builtin_amdgcn_s_sleep(1);
  }
}

__global__ __launch_bounds__(256, 1) void ncp_main(MainP P) {
  const int tid = threadIdx.x;
  const int lane = tid & 63;
  const int wv = tid >> 6;
  const int role = wv & 1;
  const int tslot = wv >> 1;
  const int wg = blockIdx.x;
  const int mt = wg / NWG_MT;     // 0..3
  const int r  = wg % NWG_MT;     // 0..9: L0, 10..16: L1, 17..32: L2

  __shared__ __align__(16) ushort_t Alds[2688 * 8];  // 42 KB staging (L0 layout)
  __shared__ __align__(16) f32x4 pacc[2][256];       // 8 KB partials (dense)

  // ---- spread flags: wf[r*16], mtile stride 1024 unsigned (4KB) ----
  unsigned* wf = P.bar + mt * 1024;
  int wa, wb;                       // pre-wait (producers) range
  int ma, mb;                       // mid-wait (residual WAR readers) range
  if (r < 10)      { wa = 0;  wb = 10; ma = 10; mb = 17; }
  else if (r < 17) { wa = 0;  wb = 17; ma = 17; mb = 33; }
  else             { wa = 10; wb = 33; ma = 0;  mb = 0;  }

  // ---- per-wave tile/validity ----
  int nt = 0;
  bool valid = true;
  if (r < 10)      nt = r * 2 + tslot;
  else if (r < 17) { nt = (r - 10) * 2 + tslot; valid = (nt < 13); }
  else             nt = (r - 17) * 2 + tslot;

  // ---- one-time weight preload into registers ----
  short8 wreg[MAXKB][4];
  if (valid) {
    if (r < 10) {
      const ushort_t* bp = P.pack + PACK0 + (size_t)nt * 26 * 2048 + (role ? 13 : 0) * 2048;
      load_w<13>(bp, lane, wreg);
    } else if (r < 17) {
      const ushort_t* bp = P.pack + PACK1 + (size_t)nt * 17 * 2048;
      if (role == 0) load_w<9>(bp, lane, wreg);
      else           load_w<8>(bp + 9 * 2048, lane, wreg);
    } else {
      const ushort_t* bp = P.pack + PACK2 + (size_t)nt * 23 * 2048;
      if (role == 0) load_w<12>(bp, lane, wreg);
      else           load_w<11>(bp + 12 * 2048, lane, wreg);
    }
  }

  if (r < 10) stage_xn(Alds, P, mt, tid, 0);  // prologue XN(0) into parity-0

  for (int s = 0; s < T_STEPS + 2; ++s) {
    // ---- pre-wait: producers' wf >= s ----
    if (wv == 0) poll_wf(wf, wa, wb - wa, lane, (unsigned)s);
    __syncthreads();

    // ---- per-layer slot state ----
    int tstep = 0;
    bool on = false;
    if (r < 10)      { tstep = s;     on = (s < T_STEPS); }
    else if (r < 17) { tstep = s - 1; on = (s >= 1 && s <= T_STEPS) && valid; }
    else             { tstep = s - 2; on = (s >= 2); }
    const bool last = (tstep == T_STEPS - 1);

    // ---- stage ----
    if (r < 10) {
      if (s < T_STEPS)
        stage2<640, 320, 0, 0>(Alds + 2048 * 8,
                               P.hi + (((s - 1) & 1) * 64 + mt * 16) * 320,
                               nullptr, nullptr, tid);
    } else if (r < 17) {
      if (s >= 1 && s <= T_STEPS)
        stage2<640, 320, 448, 224>(Alds, P.hi + (((s - 1) & 1) * 64 + mt * 16) * 320,
                                   Alds + 640 * 8,
                                   P.hc + (((s - 2) & 1) * 64 + mt * 16) * 224, tid);
    } else {
      if (s >= 2)
        stage2<448, 224, 1024, 512>(Alds, P.hc + (((s - 2) & 1) * 64 + mt * 16) * 224,
                                    Alds + 448 * 8,
                                    P.hm + (((s - 3) & 1) * 64 + mt * 16) * 512, tid);
    }
    __syncthreads();                      // (A) LDS staged

    // ---- spans (register-resident weights) ----
    f32x4 A[4];
#pragma unroll
    for (int j = 0; j < 4; ++j) A[j] = {0.f, 0.f, 0.f, 0.f};
    if (on) {
      if (r < 10) {
        const ushort_t* XNc = Alds + (s & 1) * (1024 * 8);
        const ushort_t* HIl = Alds + 2048 * 8;
        if (role == 0) span_reg<13>(wreg, XNc, lane, A[0], A[1], A[2], A[3]);
        else { span_reg<3>(wreg, XNc + 13 * 512, lane, A[0], A[1], A[2], A[3]);
               span_reg<10>(wreg + 3, HIl, lane, A[0], A[1], A[2], A[3]); }
      } else if (r < 17) {
        const ushort_t* HIr = Alds;
        const ushort_t* HCr = Alds + 640 * 8;
        if (role == 0) span_reg<9>(wreg, HIr, lane, A[0], A[1], A[2], A[3]);
        else { span_reg<1>(wreg, HIr + 9 * 512, lane, A[0], A[1], A[2], A[3]);
               span_reg<7>(wreg + 1, HCr, lane, A[0], A[1], A[2], A[3]); }
      } else {
        const ushort_t* HCr = Alds;
        const ushort_t* HMr = Alds + 448 * 8;
        if (role == 0) { span_reg<7>(wreg, HCr, lane, A[0], A[1], A[2], A[3]);
                         span_reg<5>(wreg + 7, HMr, lane, A[0], A[1], A[2], A[3]); }
        else           span_reg<11>(wreg, HMr + 5 * 512, lane, A[0], A[1], A[2], A[3]);
      }
      if (role == 1) {
#pragma unroll
        for (int j = 0; j < 4; ++j) pacc[tslot][j * 64 + lane] = A[j];
      }
    }
    __syncthreads();                      // (A2) partner accumulator ready

    // ---- mid-wait (writer waves only): residual WAR readers' wf >= s ----
    // hidden under the spans just completed; no extra __syncthreads needed.
    float vk[4];
    if (on && role == 0) {
      if (mb > ma) poll_wf(wf, ma, mb - ma, lane, (unsigned)s);
#pragma unroll
      for (int j = 0; j < 4; ++j) {
        f32x4 p = pacc[tslot][j * 64 + lane];
        A[j][0] += p[0]; A[j][1] += p[1]; A[j][2] += p[2]; A[j][3] += p[3];
      }
      if (r < 10)
        epi_h<308, 320>(A, nt, lane, mt, P.bias[0], P.bias[1], P.bias[2], P.bias[3],
                        P.hi + (tstep & 1) * HI_P, vk);
      else if (r < 17)
        epi_h<204, 224>(A, nt, lane, mt, P.bias[4], P.bias[5], P.bias[6], P.bias[7],
                        P.hc + (tstep & 1) * HC_P, vk);
      else
        epi_h<512, 512>(A, nt, lane, mt, P.bias[8], P.bias[9], P.bias[10], P.bias[11],
                        P.hm + (tstep & 1) * HM_P, vk);
    }
    asm volatile("s_waitcnt vmcnt(0)" ::: "memory");
    __syncthreads();                      // (B) all h stores at coherent point
    if (tid == 0) stf(wf + r * 16, (unsigned)(s + 1));

    // ---- off critical path: deferred y/hfin stores (nontemporal) ----
    if (on && role == 0) {
      const int n_ = nt * 16 + (lane & 15);
      const int r0 = (lane >> 4) << 2;
      const int H_ = (r < 10) ? 308 : ((r < 17) ? 204 : 512);
      const int hoff = (r < 10) ? 0 : ((r < 17) ? 308 : 512);
      if (n_ < H_) {
#pragma unroll
        for (int j = 0; j < 4; ++j) {
          const int brow = mt * 16 + r0 + j;
          if (r >= 17)
            __builtin_nontemporal_store(vk[j], &P.y[((size_t)brow * T_STEPS + tstep) * 512 + n_]);
          if (last)
            __builtin_nontemporal_store(vk[j], &P.hfin[brow * 1024 + hoff + n_]);
        }
      }
    }

    // ---- off critical path: L0 prefetches XN(s+1) into other parity ----
    if (r < 10 && s + 1 < T_STEPS)
      stage_xn(Alds + ((s + 1) & 1) * (1024 * 8), P, mt, tid, s + 1);
  }
}

extern "C" void kernel_launch(void* const* d_in, const int* in_sizes, int n_in,
                              void* d_out, int out_size, void* d_ws, size_t ws_size,
                              hipStream_t stream) {
  const float* x     = (const float*)d_in[27];
  const float* h0    = (const float*)d_in[28];
  const float* gamma = (const float*)d_in[29];
  const float* beta  = (const float*)d_in[30];

  char* ws = (char*)d_ws;
  unsigned* bar = (unsigned*)(ws + WS_BAR);
  float* mu   = (float*)(ws + WS_MU);
  float* rstd = (float*)(ws + WS_RSTD);
  ushort_t* hi = (ushort_t*)(ws + WS_HI);
  ushort_t* hc = (ushort_t*)(ws + WS_HC);
  ushort_t* hm = (ushort_t*)(ws + WS_HM);
  ushort_t* pack = (ushort_t*)(ws + WS_PACK);

  float* y = (float*)d_out;
  float* hfin = y + (size_t)64 * 1024 * 512;

  hipMemsetAsync(bar, 0, 16384, stream);

  ln_stats<<<dim3(16384), dim3(256), 0, stream>>>(x, mu, rstd);
  init_h<<<dim3(264), dim3(256), 0, stream>>>(h0, hi, hc, hm);

  PackP pp;
  for (int l = 0; l < 3; ++l) {
    for (int m = 0; m < 4; ++m) pp.w[l * 4 + m] = (const float*)d_in[l * 9 + 2 * m];
    pp.msk[l] = (const float*)d_in[l * 9 + 8];
  }
  pp.pack = pack;
  ncp_pack<<<dim3(1477), dim3(256), 0, stream>>>(pp);

  MainP mp;
  mp.x = x; mp.gamma = gamma; mp.beta = beta;
  for (int l = 0; l < 3; ++l)
    for (int m = 0; m < 4; ++m) mp.bias[l * 4 + m] = (const float*)d_in[l * 9 + 2 * m + 1];
  mp.mu = mu; mp.rstd = rstd;
  mp.hi = hi; mp.hc = hc; mp.hm = hm;
  mp.pack = pack; mp.bar = bar;
  mp.y = y; mp.hfin = hfin;
  ncp_main<<<dim3(NWG), dim3(256), 0, stream>>>(mp);
}

// Round 15
// 6650.048 us; speedup vs baseline: 2.8953x; 1.0121x over previous
//
#include <hip/hip_runtime.h>

typedef __attribute__((ext_vector_type(8))) short short8;
typedef __attribute__((ext_vector_type(4))) float f32x4;
typedef unsigned short ushort_t;
typedef unsigned long long u64_t;

#define T_STEPS 1024
#define NWG 132
#define NWG_MT 33

// r13/r14 structure (weights-in-registers, 33 WGs/mtile, 2 tiles/WG,
// wave-pair K-split, spread wf flags). r15: 4-DEEP h buffers (parity = step
// mod 4) -> all WAR guards relax to >= s-2 (free, 2 slots early), mid-wait
// REMOVED, layers fully decoupled; critical cycle = single-layer self-loop.
// Waits at slot s (single poll, two thresholds):
//   L0: wf[0,10) >= s   ; wf[10,17) >= s-2   (hi buf s&3 prior readers @s-3)
//   L1: wf[0,17) >= s   ; wf[17,33) >= s-2   (hc buf (s-1)&3 prior readers)
//   L2: wf[10,33) >= s                       (own range covers hm WAR >= s-2)
// Buffer audit (4-deep): hi buf b=s&3 prior hi(s-4) read @slot s-3 by L0/L1
// stage -> wf >= s-2 ok. hc buf (s-1)&3 prior hc(s-5) read @s-3 by L1/L2 ->
// L1 covered by [10,17)>=s, L2 by [17,33)>=s-2. hm buf (s-2)&3 prior hm(s-6)
// read @s-3 by L2 -> [17,33)>=s covers. Flags post at slot END -> conservative.

#define PACK0 0
#define PACK1 1064960            // 20*26*2048
#define PACK2 1517568            // PACK1 + 13*17*2048

#define HI_P (64*320)
#define HC_P (64*224)
#define HM_P (64*512)

// ws offsets (bytes)
#define WS_BAR   0               // 4 mtiles x 4KB spread flags
#define WS_MU    16384
#define WS_RSTD  278528
#define WS_HI    540672          // 4*HI_P*2 = 163840 -> 704512
#define WS_HC    704512          // 4*HC_P*2 = 114688 -> 819200
#define WS_HM    819200          // 4*HM_P*2 = 262144 -> 1081344
#define WS_PACK  1081344         // + 6049792 -> ends 7131136

__device__ __forceinline__ ushort_t f2bf(float f) {
  union { float f; unsigned u; } un; un.f = f;
  unsigned r = (un.u + 0x7fffu + ((un.u >> 16) & 1u)) >> 16;
  return (ushort_t)r;
}

__device__ __forceinline__ void st2(ushort_t* p, ushort_t v) {
  __hip_atomic_store(p, v, __ATOMIC_RELAXED, __HIP_MEMORY_SCOPE_SYSTEM);
}
__device__ __forceinline__ u64_t ld8(const ushort_t* p) {
  return __hip_atomic_load((const u64_t*)p, __ATOMIC_RELAXED, __HIP_MEMORY_SCOPE_SYSTEM);
}
__device__ __forceinline__ unsigned ldf(const unsigned* p) {
  return __hip_atomic_load(p, __ATOMIC_RELAXED, __HIP_MEMORY_SCOPE_SYSTEM);
}
__device__ __forceinline__ void stf(unsigned* p, unsigned v) {
  __hip_atomic_store(p, v, __ATOMIC_RELAXED, __HIP_MEMORY_SCOPE_SYSTEM);
}

// ---------------- LayerNorm stats ----------------
__global__ __launch_bounds__(256) void ln_stats(const float* __restrict__ x,
                                                float* __restrict__ mu,
                                                float* __restrict__ rstd) {
  const int row = blockIdx.x * 4 + (threadIdx.x >> 6);
  const int lane = threadIdx.x & 63;
  const float* xr = x + (size_t)row * 512;
  float4 v0 = *(const float4*)(xr + lane * 8);
  float4 v1 = *(const float4*)(xr + lane * 8 + 4);
  float s = v0.x + v0.y + v0.z + v0.w + v1.x + v1.y + v1.z + v1.w;
  float q = v0.x*v0.x + v0.y*v0.y + v0.z*v0.z + v0.w*v0.w
          + v1.x*v1.x + v1.y*v1.y + v1.z*v1.z + v1.w*v1.w;
  for (int m = 1; m <= 32; m <<= 1) {
    s += __shfl_xor(s, m, 64);
    q += __shfl_xor(q, m, 64);
  }
  if (lane == 0) {
    float mean = s * (1.f / 512.f);
    float var = q * (1.f / 512.f) - mean * mean;
    mu[row] = mean;
    rstd[row] = rsqrtf(var + 1e-5f);
  }
}

// -------- init hidden state: bf16 linear padded, ALL FOUR parities --------
__global__ void init_h(const float* __restrict__ h0,
                       ushort_t* hi, ushort_t* hc, ushort_t* hm) {
  int i = blockIdx.x * 256 + threadIdx.x;
  if (i >= 64 * 1056) return;
  int b = i / 1056, c = i % 1056;
  if (c < 320) {
    ushort_t v = (c < 308) ? f2bf(h0[b * 1024 + c]) : 0;
#pragma unroll
    for (int p = 0; p < 4; ++p) st2(hi + p * HI_P + b * 320 + c, v);
  } else if (c < 544) {
    int col = c - 320;
    ushort_t v = (col < 204) ? f2bf(h0[b * 1024 + 308 + col]) : 0;
#pragma unroll
    for (int p = 0; p < 4; ++p) st2(hc + p * HC_P + b * 224 + col, v);
  } else {
    int col = c - 544;
    ushort_t v = f2bf(h0[b * 1024 + 512 + col]);
#pragma unroll
    for (int p = 0; p < 4; ++p) st2(hm + p * HM_P + b * 512 + col, v);
  }
}

// ---------------- pack masked weights ----------------
struct PackP {
  const float* w[12];
  const float* msk[3];
  ushort_t* pack;
};

__global__ __launch_bounds__(256) void ncp_pack(PackP P) {
  int u = blockIdx.x * 256 + threadIdx.x;
  int layer, rem, KB, K, H, s0p, s0l, s1l;
  size_t base;
  if (u < 133120)      { layer = 0; rem = u;          KB = 26; K = 820; H = 308; s0p = 512; s0l = 512; s1l = 308; base = PACK0; }
  else if (u < 189696) { layer = 1; rem = u - 133120; KB = 17; K = 512; H = 204; s0p = 320; s0l = 308; s1l = 204; base = PACK1; }
  else if (u < 378112) { layer = 2; rem = u - 189696; KB = 23; K = 716; H = 512; s0p = 224; s0l = 204; s1l = 512; base = PACK2; }
  else return;
  const int lane = rem & 63;
  const int mat = (rem >> 6) & 3;
  const int kb = (rem >> 8) % KB;
  const int nt = (rem >> 8) / KB;
  const float* W = P.w[layer * 4 + mat];
  const float* M = (mat < 2) ? P.msk[layer] : nullptr;
  const int n = nt * 16 + (lane & 15);
  const int kbase = kb * 32 + ((lane >> 4) << 3);
  ushort_t* dst = P.pack + base + (size_t)rem * 8;
#pragma unroll
  for (int j = 0; j < 8; ++j) {
    const int kp = kbase + j;
    int ko;
    if (kp < s0p) ko = (kp < s0l) ? kp : -1;
    else { const int ks = kp - s0p; ko = (ks < s1l) ? (s0l + ks) : -1; }
    float v = 0.f;
    if (n < H && ko >= 0) {
      v = W[(size_t)n * K + ko];
      if (M) v *= M[(size_t)n * K + ko];
    }
    dst[j] = f2bf(v);
  }
}

// ---------------- main persistent kernel ----------------
struct MainP {
  const float* x;
  const float* gamma;
  const float* beta;
  const float* bias[12];
  const float* mu;
  const float* rstd;
  ushort_t* hi;
  ushort_t* hc;
  ushort_t* hm;
  const ushort_t* pack;
  unsigned* bar;
  float* y;
  float* hfin;
};

#define MAXKB 13

template<int KBT>
__device__ __forceinline__ void load_w(const ushort_t* __restrict__ bp, int lane,
                                       short8 (*w)[4]) {
#pragma unroll
  for (int kb = 0; kb < KBT; ++kb) {
    const ushort_t* q = bp + (size_t)kb * 2048 + lane * 8;
    w[kb][0] = *(const short8*)(q);
    w[kb][1] = *(const short8*)(q + 512);
    w[kb][2] = *(const short8*)(q + 1024);
    w[kb][3] = *(const short8*)(q + 1536);
  }
}

template<int KBT>
__device__ __forceinline__ void span_reg(const short8 (*w)[4],
                                         const ushort_t* __restrict__ lds, int lane,
                                         f32x4& a0, f32x4& a1, f32x4& a2, f32x4& a3) {
#pragma unroll
  for (int kb = 0; kb < KBT; ++kb) {
    short8 av = *(const short8*)(lds + (size_t)(kb * 64 + lane) * 8);
    a0 = __builtin_amdgcn_mfma_f32_16x16x32_bf16(av, w[kb][0], a0, 0, 0, 0);
    a1 = __builtin_amdgcn_mfma_f32_16x16x32_bf16(av, w[kb][1], a1, 0, 0, 0);
    a2 = __builtin_amdgcn_mfma_f32_16x16x32_bf16(av, w[kb][2], a2, 0, 0, 0);
    a3 = __builtin_amdgcn_mfma_f32_16x16x32_bf16(av, w[kb][3], a3, 0, 0, 0);
  }
}

template<int H, int STP>
__device__ __forceinline__ void epi_h(const f32x4* A, int nt, int lane, int mtile,
                                      const float* __restrict__ bp1, const float* __restrict__ bp2,
                                      const float* __restrict__ bpa, const float* __restrict__ bpb,
                                      ushort_t* __restrict__ hout, float* vk) {
  const int n = nt * 16 + (lane & 15);
  const int r0 = (lane >> 4) << 2;
#pragma unroll
  for (int j = 0; j < 4; ++j) vk[j] = 0.f;
  if (n < H) {
    float c1 = bp1[n], c2 = bp2[n], ca = bpa[n], cb = bpb[n];
#pragma unroll
    for (int j = 0; j < 4; ++j) {
      int brow = mtile * 16 + r0 + j;
      float sg = 1.f / (1.f + __expf(-(A[2][j] + ca + A[3][j] + cb)));
      float f1 = 1.f - 2.f / (1.f + __expf(2.f * (A[0][j] + c1)));
      float f2 = 1.f - 2.f / (1.f + __expf(2.f * (A[1][j] + c2)));
      float v = f1 * (1.f - sg) + sg * f2;
      vk[j] = v;
      st2(hout + (size_t)brow * STP + n, f2bf(v));
    }
  }
}

template<int S1, int ST1, int S2, int ST2>
__device__ __forceinline__ void stage2(ushort_t* __restrict__ r1, const ushort_t* __restrict__ h1,
                                       ushort_t* __restrict__ r2, const ushort_t* __restrict__ h2,
                                       int tid) {
  constexpr int U1 = S1 * 2, U2 = S2 * 2;
  constexpr int I1 = (U1 + 255) / 256;
  constexpr int I2 = (U2 + 255) / 256;
  u64_t a[I1];
  u64_t b[I2 > 0 ? I2 : 1];
#pragma unroll
  for (int i = 0; i < I1; ++i) {
    const int u = tid + i * 256;
    if ((U1 & 255) == 0 || u < U1) {
      const int slot = u >> 1;
      a[i] = ld8(h1 + (slot & 15) * ST1 + (slot >> 6) * 32 + ((slot >> 4) & 3) * 8 + (u & 1) * 4);
    }
  }
  if constexpr (S2 > 0) {
#pragma unroll
    for (int i = 0; i < I2; ++i) {
      const int u = tid + i * 256;
      if ((U2 & 255) == 0 || u < U2) {
        const int slot = u >> 1;
        b[i] = ld8(h2 + (slot & 15) * ST2 + (slot >> 6) * 32 + ((slot >> 4) & 3) * 8 + (u & 1) * 4);
      }
    }
  }
#pragma unroll
  for (int i = 0; i < I1; ++i) {
    const int u = tid + i * 256;
    if ((U1 & 255) == 0 || u < U1) *(u64_t*)(r1 + (size_t)u * 4) = a[i];
  }
  if constexpr (S2 > 0) {
#pragma unroll
    for (int i = 0; i < I2; ++i) {
      const int u = tid + i * 256;
      if ((U2 & 255) == 0 || u < U2) *(u64_t*)(r2 + (size_t)u * 4) = b[i];
    }
  }
}

__device__ __forceinline__ void stage_xn(ushort_t* __restrict__ XN, const MainP& P,
                                         int mtile, int tid, int t) {
#pragma unroll
  for (int i = 0; i < 4; ++i) {
    const int s = tid + i * 256;
    const int ln = s & 63;
    const int brow = mtile * 16 + (ln & 15);
    const int kbase = (s >> 6) * 32 + ((ln >> 4) << 3);
    const float muv = P.mu[brow * T_STEPS + t];
    const float rsv = P.rstd[brow * T_STEPS + t];
    const f32x4* xr = (const f32x4*)(P.x + ((size_t)brow * T_STEPS + t) * 512 + kbase);
    f32x4 xv0 = __builtin_nontemporal_load(xr);
    f32x4 xv1 = __builtin_nontemporal_load(xr + 1);
    const f32x4 g0 = *(const f32x4*)(P.gamma + kbase);
    const f32x4 g1 = *(const f32x4*)(P.gamma + kbase + 4);
    const f32x4 b0 = *(const f32x4*)(P.beta + kbase);
    const f32x4 b1 = *(const f32x4*)(P.beta + kbase + 4);
    short8 w;
#pragma unroll
    for (int j = 0; j < 4; ++j) w[j] = f2bf((xv0[j] - muv) * rsv * g0[j] + b0[j]);
#pragma unroll
    for (int j = 0; j < 4; ++j) w[4 + j] = f2bf((xv1[j] - muv) * rsv * g1[j] + b1[j]);
    *(short8*)(XN + (size_t)s * 8) = w;
  }
}

// wave poll: two flag ranges with separate thresholds; s_sleep(1) backoff
__device__ __forceinline__ void poll2(const unsigned* wfbase, int lane,
                                      int a1, int c1, unsigned need1,
                                      int a2, int c2, unsigned need2) {
  const unsigned* p = wfbase;
  unsigned need = 0;
  bool act = false;
  if (lane < c1)           { p = wfbase + (a1 + lane) * 16;        need = need1; act = true; }
  else if (lane < c1 + c2) { p = wfbase + (a2 + lane - c1) * 16;   need = need2; act = true; }
  for (;;) {
    unsigned v = act ? ldf(p) : 0xFFFFFFFFu;
    if (__all((int)(v >= need))) break;
    __builtin_amdgcn_s_sleep(1);
  }
}

__global__ __launch_bounds__(256, 1) void ncp_main(MainP P) {
  const int tid = threadIdx.x;
  const int lane = tid & 63;
  const int wv = tid >> 6;
  const int role = wv & 1;
  const int tslot = wv >> 1;
  const int wg = blockIdx.x;
  const int mt = wg / NWG_MT;     // 0..3
  const int r  = wg % NWG_MT;     // 0..9: L0, 10..16: L1, 17..32: L2

  __shared__ __align__(16) ushort_t Alds[2688 * 8];  // 42 KB staging (L0 layout)
  __shared__ __align__(16) f32x4 pacc[2][256];       // 8 KB partials (dense)

  // ---- spread flags: wf[r*16], mtile stride 1024 unsigned (4KB) ----
  unsigned* wf = P.bar + mt * 1024;
  // poll ranges: (a1,c1)@>=s  (a2,c2)@>=s-2
  int a1, c1, a2, c2;
  if (r < 10)      { a1 = 0;  c1 = 10; a2 = 10; c2 = 7;  }
  else if (r < 17) { a1 = 0;  c1 = 17; a2 = 17; c2 = 16; }
  else             { a1 = 10; c1 = 23; a2 = 0;  c2 = 0;  }

  // ---- per-wave tile/validity ----
  int nt = 0;
  bool valid = true;
  if (r < 10)      nt = r * 2 + tslot;
  else if (r < 17) { nt = (r - 10) * 2 + tslot; valid = (nt < 13); }
  else             nt = (r - 17) * 2 + tslot;

  // ---- one-time weight preload into registers ----
  short8 wreg[MAXKB][4];
  if (valid) {
    if (r < 10) {
      const ushort_t* bp = P.pack + PACK0 + (size_t)nt * 26 * 2048 + (role ? 13 : 0) * 2048;
      load_w<13>(bp, lane, wreg);
    } else if (r < 17) {
      const ushort_t* bp = P.pack + PACK1 + (size_t)nt * 17 * 2048;
      if (role == 0) load_w<9>(bp, lane, wreg);
      else           load_w<8>(bp + 9 * 2048, lane, wreg);
    } else {
      const ushort_t* bp = P.pack + PACK2 + (size_t)nt * 23 * 2048;
      if (role == 0) load_w<12>(bp, lane, wreg);
      else           load_w<11>(bp + 12 * 2048, lane, wreg);
    }
  }

  if (r < 10) stage_xn(Alds, P, mt, tid, 0);  // prologue XN(0) into parity-0

  for (int s = 0; s < T_STEPS + 2; ++s) {
    // ---- pre-wait: RAW >= s, relaxed WAR >= s-2 (single poll) ----
    if (wv == 0) {
      const unsigned needA = (unsigned)s;
      const unsigned needB = (s >= 2) ? (unsigned)(s - 2) : 0u;
      poll2(wf, lane, a1, c1, needA, a2, c2, needB);
    }
    __syncthreads();

    // ---- per-layer slot state ----
    int tstep = 0;
    bool on = false;
    if (r < 10)      { tstep = s;     on = (s < T_STEPS); }
    else if (r < 17) { tstep = s - 1; on = (s >= 1 && s <= T_STEPS) && valid; }
    else             { tstep = s - 2; on = (s >= 2); }
    const bool last = (tstep == T_STEPS - 1);

    // ---- stage (4-deep parity: step mod 4) ----
    if (r < 10) {
      if (s < T_STEPS)
        stage2<640, 320, 0, 0>(Alds + 2048 * 8,
                               P.hi + (((s - 1) & 3) * 64 + mt * 16) * 320,
                               nullptr, nullptr, tid);
    } else if (r < 17) {
      if (s >= 1 && s <= T_STEPS)
        stage2<640, 320, 448, 224>(Alds, P.hi + (((s - 1) & 3) * 64 + mt * 16) * 320,
                                   Alds + 640 * 8,
                                   P.hc + (((s - 2) & 3) * 64 + mt * 16) * 224, tid);
    } else {
      if (s >= 2)
        stage2<448, 224, 1024, 512>(Alds, P.hc + (((s - 2) & 3) * 64 + mt * 16) * 224,
                                    Alds + 448 * 8,
                                    P.hm + (((s - 3) & 3) * 64 + mt * 16) * 512, tid);
    }
    __syncthreads();                      // (A) LDS staged

    // ---- spans (register-resident weights) ----
    f32x4 A[4];
#pragma unroll
    for (int j = 0; j < 4; ++j) A[j] = {0.f, 0.f, 0.f, 0.f};
    if (on) {
      if (r < 10) {
        const ushort_t* XNc = Alds + (s & 1) * (1024 * 8);
        const ushort_t* HIl = Alds + 2048 * 8;
        if (role == 0) span_reg<13>(wreg, XNc, lane, A[0], A[1], A[2], A[3]);
        else { span_reg<3>(wreg, XNc + 13 * 512, lane, A[0], A[1], A[2], A[3]);
               span_reg<10>(wreg + 3, HIl, lane, A[0], A[1], A[2], A[3]); }
      } else if (r < 17) {
        const ushort_t* HIr = Alds;
        const ushort_t* HCr = Alds + 640 * 8;
        if (role == 0) span_reg<9>(wreg, HIr, lane, A[0], A[1], A[2], A[3]);
        else { span_reg<1>(wreg, HIr + 9 * 512, lane, A[0], A[1], A[2], A[3]);
               span_reg<7>(wreg + 1, HCr, lane, A[0], A[1], A[2], A[3]); }
      } else {
        const ushort_t* HCr = Alds;
        const ushort_t* HMr = Alds + 448 * 8;
        if (role == 0) { span_reg<7>(wreg, HCr, lane, A[0], A[1], A[2], A[3]);
                         span_reg<5>(wreg + 7, HMr, lane, A[0], A[1], A[2], A[3]); }
        else           span_reg<11>(wreg, HMr + 5 * 512, lane, A[0], A[1], A[2], A[3]);
      }
      if (role == 1) {
#pragma unroll
        for (int j = 0; j < 4; ++j) pacc[tslot][j * 64 + lane] = A[j];
      }
    }
    __syncthreads();                      // (A2) partner accumulator ready

    // ---- epilogue: h-stores only (no mid-wait; WAR covered by pre-wait) ----
    float vk[4];
    if (on && role == 0) {
#pragma unroll
      for (int j = 0; j < 4; ++j) {
        f32x4 p = pacc[tslot][j * 64 + lane];
        A[j][0] += p[0]; A[j][1] += p[1]; A[j][2] += p[2]; A[j][3] += p[3];
      }
      if (r < 10)
        epi_h<308, 320>(A, nt, lane, mt, P.bias[0], P.bias[1], P.bias[2], P.bias[3],
                        P.hi + (tstep & 3) * HI_P, vk);
      else if (r < 17)
        epi_h<204, 224>(A, nt, lane, mt, P.bias[4], P.bias[5], P.bias[6], P.bias[7],
                        P.hc + (tstep & 3) * HC_P, vk);
      else
        epi_h<512, 512>(A, nt, lane, mt, P.bias[8], P.bias[9], P.bias[10], P.bias[11],
                        P.hm + (tstep & 3) * HM_P, vk);
    }
    asm volatile("s_waitcnt vmcnt(0)" ::: "memory");
    __syncthreads();                      // (B) all h stores at coherent point
    if (tid == 0) stf(wf + r * 16, (unsigned)(s + 1));

    // ---- off critical path: deferred y/hfin stores (nontemporal) ----
    if (on && role == 0) {
      const int n_ = nt * 16 + (lane & 15);
      const int r0 = (lane >> 4) << 2;
      const int H_ = (r < 10) ? 308 : ((r < 17) ? 204 : 512);
      const int hoff = (r < 10) ? 0 : ((r < 17) ? 308 : 512);
      if (n_ < H_) {
#pragma unroll
        for (int j = 0; j < 4; ++j) {
          const int brow = mt * 16 + r0 + j;
          if (r >= 17)
            __builtin_nontemporal_store(vk[j], &P.y[((size_t)brow * T_STEPS + tstep) * 512 + n_]);
          if (last)
            __builtin_nontemporal_store(vk[j], &P.hfin[brow * 1024 + hoff + n_]);
        }
      }
    }

    // ---- off critical path: L0 prefetches XN(s+1) into other parity ----
    if (r < 10 && s + 1 < T_STEPS)
      stage_xn(Alds + ((s + 1) & 1) * (1024 * 8), P, mt, tid, s + 1);
  }
}

extern "C" void kernel_launch(void* const* d_in, const int* in_sizes, int n_in,
                              void* d_out, int out_size, void* d_ws, size_t ws_size,
                              hipStream_t stream) {
  const float* x     = (const float*)d_in[27];
  const float* h0    = (const float*)d_in[28];
  const float* gamma = (const float*)d_in[29];
  const float* beta  = (const float*)d_in[30];

  char* ws = (char*)d_ws;
  unsigned* bar = (unsigned*)(ws + WS_BAR);
  float* mu   = (float*)(ws + WS_MU);
  float* rstd = (float*)(ws + WS_RSTD);
  ushort_t* hi = (ushort_t*)(ws + WS_HI);
  ushort_t* hc = (ushort_t*)(ws + WS_HC);
  ushort_t* hm = (ushort_t*)(ws + WS_HM);
  ushort_t* pack = (ushort_t*)(ws + WS_PACK);

  float* y = (float*)d_out;
  float* hfin = y + (size_t)64 * 1024 * 512;

  hipMemsetAsync(bar, 0, 16384, stream);

  ln_stats<<<dim3(16384), dim3(256), 0, stream>>>(x, mu, rstd);
  init_h<<<dim3(264), dim3(256), 0, stream>>>(h0, hi, hc, hm);

  PackP pp;
  for (int l = 0; l < 3; ++l) {
    for (int m = 0; m < 4; ++m) pp.w[l * 4 + m] = (const float*)d_in[l * 9 + 2 * m];
    pp.msk[l] = (const float*)d_in[l * 9 + 8];
  }
  pp.pack = pack;
  ncp_pack<<<dim3(1477), dim3(256), 0, stream>>>(pp);

  MainP mp;
  mp.x = x; mp.gamma = gamma; mp.beta = beta;
  for (int l = 0; l < 3; ++l)
    for (int m = 0; m < 4; ++m) mp.bias[l * 4 + m] = (const float*)d_in[l * 9 + 2 * m + 1];
  mp.mu = mu; mp.rstd = rstd;
  mp.hi = hi; mp.hc = hc; mp.hm = hm;
  mp.pack = pack; mp.bar = bar;
  mp.y = y; mp.hfin = hfin;
  ncp_main<<<dim3(NWG), dim3(256), 0, stream>>>(mp);
}